// Round 2
// baseline (37422.452 us; speedup 1.0000x reference)
//
#include <hip/hip_runtime.h>
#include <cstdint>
#include <cstddef>

#define DEV __device__ __forceinline__

typedef unsigned short u16;
typedef __attribute__((ext_vector_type(8))) short short8;
typedef __attribute__((ext_vector_type(4))) float floatx4;

DEV float bf2f(u16 h) { union { unsigned u; float f; } c; c.u = ((unsigned)h) << 16; return c.f; }
DEV u16 f2bf(float f) {
  union { float f; unsigned u; } c; c.f = f;
  unsigned r = 0x7fffu + ((c.u >> 16) & 1u);
  return (u16)((c.u + r) >> 16);
}
DEV short8 ld8(const u16* p) { return *(const short8*)p; }
DEV floatx4 mfma16(short8 a, short8 b, floatx4 c) {
  return __builtin_amdgcn_mfma_f32_16x16x32_bf16(a, b, c, 0, 0, 0);
}
DEV void async16(const u16* g, u16* l) {
  __builtin_amdgcn_global_load_lds((__attribute__((address_space(1))) void*)(uintptr_t)(const void*)g,
                                   (__attribute__((address_space(3))) void*)(uintptr_t)(void*)l, 16, 0, 0);
}
DEV float sigm(float x) { return 1.f / (1.f + __expf(-x)); }

DEV float blk_sum256(float v) {
  __shared__ float sh[4];
  #pragma unroll
  for (int d = 32; d >= 1; d >>= 1) v += __shfl_xor(v, d, 64);
  if ((threadIdx.x & 63) == 0) sh[threadIdx.x >> 6] = v;
  __syncthreads();
  v = sh[0] + sh[1] + sh[2] + sh[3];
  __syncthreads();
  return v;
}

// ---------------- generic bf16 MFMA GEMM: C = A[M,K] * BT[N,K]^T (+bias) ----------------
template<bool RELU, bool WF32, bool WBF16, bool ACC>
__global__ __launch_bounds__(256, 2) void gemm_kernel(
    const u16* __restrict__ A, const u16* __restrict__ BT,
    const float* __restrict__ bias, float* __restrict__ Cf, u16* __restrict__ Cb,
    int M, int N, int K, int lda, int ldb, int ldc)
{
  __shared__ u16 As[4096];
  __shared__ u16 Bs[4096];
  const int tid = threadIdx.x;
  const int lane = tid & 63;
  const int w = tid >> 6;
  const int nTiles = N >> 7;
  const int bm = blockIdx.x / nTiles;
  const int bn = blockIdx.x - bm * nTiles;
  const int m0 = bm << 7, n0 = bn << 7;
  const int q = lane >> 4, lm = lane & 15;
  const int wm = (w & 1) << 6, wn = (w >> 1) << 6;

  const int s1 = tid, s2 = tid + 256;
  const int r1 = s1 >> 2, c1 = (s1 & 3) ^ ((r1 >> 2) & 3);
  const int r2 = s2 >> 2, c2 = (s2 & 3) ^ ((r2 >> 2) & 3);
  const u16* ga1 = A + (size_t)(m0 + r1) * lda + c1 * 8;
  const u16* ga2 = A + (size_t)(m0 + r2) * lda + c2 * 8;
  const u16* gb1 = BT + (size_t)(n0 + r1) * ldb + c1 * 8;
  const u16* gb2 = BT + (size_t)(n0 + r2) * ldb + c2 * 8;

  floatx4 acc[4][4] = {};

  for (int kt = 0; kt < K; kt += 32) {
    async16(ga1 + kt, &As[s1 * 8]);
    async16(ga2 + kt, &As[s2 * 8]);
    async16(gb1 + kt, &Bs[s1 * 8]);
    async16(gb2 + kt, &Bs[s2 * 8]);
    __syncthreads();
    short8 af[4], bfr[4];
    #pragma unroll
    for (int i = 0; i < 4; ++i) {
      int r = wm + i * 16 + lm;
      af[i] = ld8(&As[(r * 4 + (q ^ ((r >> 2) & 3))) * 8]);
      r = wn + i * 16 + lm;
      bfr[i] = ld8(&Bs[(r * 4 + (q ^ ((r >> 2) & 3))) * 8]);
    }
    #pragma unroll
    for (int mi = 0; mi < 4; ++mi)
      #pragma unroll
      for (int ni = 0; ni < 4; ++ni)
        acc[mi][ni] = mfma16(af[mi], bfr[ni], acc[mi][ni]);
    __syncthreads();
  }
  #pragma unroll
  for (int ni = 0; ni < 4; ++ni) {
    int col = n0 + wn + ni * 16 + lm;
    float bv = ACC ? 0.f : bias[col];
    #pragma unroll
    for (int mi = 0; mi < 4; ++mi) {
      int rowb = m0 + wm + mi * 16 + q * 4;
      #pragma unroll
      for (int r = 0; r < 4; ++r) {
        float v = acc[mi][ni][r] + bv;
        if (RELU) v = fmaxf(v, 0.f);
        size_t idx = (size_t)(rowb + r) * ldc + col;
        if (WF32) { if (ACC) Cf[idx] += v; else Cf[idx] = v; }
        if (WBF16) Cb[idx] = f2bf(v);
      }
    }
  }
}

// ---------------- weight conversion kernels ----------------
__global__ __launch_bounds__(256) void cvt_transpose_kernel(
    const float* __restrict__ src, u16* __restrict__ dst, int K, int N)
{
  __shared__ float tile[32][33];
  int n0 = blockIdx.x * 32, k0 = blockIdx.y * 32;
  int tx = threadIdx.x & 31, ty = threadIdx.x >> 5;
  #pragma unroll
  for (int i = 0; i < 32; i += 8)
    tile[ty + i][tx] = src[(size_t)(k0 + ty + i) * N + n0 + tx];
  __syncthreads();
  #pragma unroll
  for (int i = 0; i < 32; i += 8)
    dst[(size_t)(n0 + ty + i) * K + k0 + tx] = f2bf(tile[tx][ty + i]);
}

__global__ void cvt_kernel(const float* __restrict__ s, u16* __restrict__ d, int n) {
  int i = blockIdx.x * 256 + threadIdx.x;
  int stride = gridDim.x * 256;
  for (; i < n; i += stride) d[i] = f2bf(s[i]);
}

// permute gate rows: dst row q <- src row (q&3)*1024 + (q>>2)
__global__ void cvt_perm_kernel(const float* __restrict__ src, u16* __restrict__ dst, int cols) {
  int qrow = blockIdx.x;
  int orig = (qrow & 3) * 1024 + (qrow >> 2);
  const float* sp = src + (size_t)orig * cols;
  u16* dp = dst + (size_t)qrow * cols;
  for (int c = threadIdx.x; c < cols; c += 256) dp[c] = f2bf(sp[c]);
}

__global__ void bias_perm_kernel(const float* __restrict__ bih, const float* __restrict__ bhh,
                                 float* __restrict__ bsum) {
  int q = blockIdx.x * 256 + threadIdx.x;
  int orig = (q & 3) * 1024 + (q >> 2);
  bsum[q] = bih[orig] + bhh[orig];
}

// ---------------- embedding / pooling / LN ----------------
__global__ void embed_kernel(const int* __restrict__ tgt, const float* __restrict__ ce,
                             const float* __restrict__ pp, u16* __restrict__ out) {
  int row = blockIdx.x;
  int b = row / 1000, s = row - b * 1000;
  int id = (s < 5) ? 1 : tgt[b * 1000 + s - 5];
  int e = threadIdx.x;
  out[(size_t)row * 128 + e] = f2bf(ce[id * 128 + e] + pp[s * 128 + e]);
}

__global__ __launch_bounds__(256) void pool_bert_ln_kernel(
    const u16* __restrict__ hb, const float* __restrict__ tmask,
    const float* __restrict__ pos, const float* __restrict__ tok,
    const float* __restrict__ g, const float* __restrict__ bt,
    float* __restrict__ x, u16* __restrict__ xb, float* __restrict__ smaskOut)
{
  int row = blockIdx.x, b = row / 200, t = row - b * 200;
  int tid = threadIdx.x;
  float m[4] = {0.f, 0.f, 0.f, 0.f};
  float sm = 0.f;
  for (int wi = 0; wi < 5; ++wi) {
    int s = t * 5 + wi;
    float im = (s < 5) ? 1.f : tmask[b * 1000 + s - 5];
    sm = fmaxf(sm, im);
    const u16* hr = hb + (size_t)(b * 1000 + s) * 1024;
    #pragma unroll
    for (int i = 0; i < 4; ++i) {
      int d = tid + i * 256;
      m[i] = fmaxf(m[i], bf2f(hr[d]) * im);
    }
  }
  float y[4]; float ssum = 0.f;
  #pragma unroll
  for (int i = 0; i < 4; ++i) {
    int d = tid + i * 256;
    y[i] = m[i] + pos[t * 1024 + d] + tok[d];
    ssum += y[i];
  }
  float mean = blk_sum256(ssum) * (1.f / 1024.f);
  float vs = 0.f;
  #pragma unroll
  for (int i = 0; i < 4; ++i) { float dd = y[i] - mean; vs += dd * dd; }
  float var = blk_sum256(vs) * (1.f / 1024.f);
  float rs = rsqrtf(var + 1e-12f);
  #pragma unroll
  for (int i = 0; i < 4; ++i) {
    int d = tid + i * 256;
    float o = (y[i] - mean) * rs * g[d] + bt[d];
    x[(size_t)row * 1024 + d] = o;
    xb[(size_t)row * 1024 + d] = f2bf(o);
  }
  if (tid == 0) smaskOut[row] = sm;
}

__global__ __launch_bounds__(256) void resid_ln_kernel(
    float* __restrict__ x, const float* __restrict__ o,
    const float* __restrict__ g, const float* __restrict__ bt,
    u16* __restrict__ xb)
{
  size_t row = blockIdx.x;
  int tid = threadIdx.x;
  float y[4]; float s = 0.f;
  #pragma unroll
  for (int i = 0; i < 4; ++i) {
    int d = tid + i * 256;
    y[i] = x[row * 1024 + d] + o[row * 1024 + d];
    s += y[i];
  }
  float mean = blk_sum256(s) * (1.f / 1024.f);
  float vs = 0.f;
  #pragma unroll
  for (int i = 0; i < 4; ++i) { float dd = y[i] - mean; vs += dd * dd; }
  float var = blk_sum256(vs) * (1.f / 1024.f);
  float rs = rsqrtf(var + 1e-12f);
  #pragma unroll
  for (int i = 0; i < 4; ++i) {
    int d = tid + i * 256;
    float out = (y[i] - mean) * rs * g[d] + bt[d];
    x[row * 1024 + d] = out;
    xb[row * 1024 + d] = f2bf(out);
  }
}

// ---------------- attention: fused QK^T + softmax -> P (bf16) ----------------
__global__ __launch_bounds__(256) void scores_kernel(
    const u16* __restrict__ Q, int qstride,
    const u16* __restrict__ Kp, int kstride, int kcoff, int krows,
    const float* __restrict__ mask, u16* __restrict__ P, int selfmode)
{
  int wid = blockIdx.x * 4 + (threadIdx.x >> 6);
  int lane = threadIdx.x & 63;
  int qt = wid % 13, h = (wid / 13) & 15, b = wid / 208;
  int lm = lane & 15, quad = lane >> 4;
  int t0 = qt * 16;
  int trow = t0 + lm; if (trow > 199) trow = 199;
  const u16* qp = Q + (size_t)(b * 200 + trow) * qstride + h * 64;
  short8 a0 = ld8(qp + quad * 8);
  short8 a1 = ld8(qp + 32 + quad * 8);
  floatx4 S[16];
  const int nmf = selfmode ? 13 : 16;
  for (int ut = 0; ut < nmf; ++ut) {
    int ur = ut * 16 + lm; if (ur >= krows) ur = krows - 1;
    const u16* kp = Kp + (size_t)(b * krows + ur) * kstride + kcoff + h * 64;
    floatx4 z = {0.f, 0.f, 0.f, 0.f};
    z = mfma16(a0, ld8(kp + quad * 8), z);
    z = mfma16(a1, ld8(kp + 32 + quad * 8), z);
    S[ut] = z;
  }
  for (int ut = nmf; ut < 16; ++ut) S[ut] = (floatx4){0.f, 0.f, 0.f, 0.f};
  const float scale = 0.125f;
  u16* prow_base = P + (size_t)((b * 16 + h) * 200) * 256;
  for (int r = 0; r < 4; ++r) {
    int t = t0 + quad * 4 + r;
    float mx = -3e38f;
    float vv[16];
    #pragma unroll
    for (int ut = 0; ut < 16; ++ut) {
      int u = ut * 16 + lm;
      float bias;
      if (selfmode) {
        bias = ((u <= t && u < 200) ? 0.f : -1e9f);
        if (u < 200) bias += (1.f - mask[b * 200 + u]) * -1e9f;
      } else {
        bias = (1.f - mask[b * 256 + u]) * -1e9f;
      }
      float v = S[ut][r] * scale + bias;
      vv[ut] = v;
      mx = fmaxf(mx, v);
    }
    #pragma unroll
    for (int d = 1; d < 16; d <<= 1) mx = fmaxf(mx, __shfl_xor(mx, d, 64));
    float sum = 0.f;
    #pragma unroll
    for (int ut = 0; ut < 16; ++ut) { float e = __expf(vv[ut] - mx); vv[ut] = e; sum += e; }
    #pragma unroll
    for (int d = 1; d < 16; d <<= 1) sum += __shfl_xor(sum, d, 64);
    float inv = 1.f / sum;
    if (t < 200) {
      u16* pr = prow_base + (size_t)t * 256;
      #pragma unroll
      for (int ut = 0; ut < 16; ++ut) pr[ut * 16 + lm] = f2bf(vv[ut] * inv);
    }
  }
}

// transpose V slice -> vT[b,h,64,256]
__global__ __launch_bounds__(256) void vtrans_kernel(
    const u16* __restrict__ src, int stride, int coff, int krows, u16* __restrict__ vT)
{
  int b = blockIdx.x >> 4, h = blockIdx.x & 15;
  __shared__ u16 tile[64][257];
  for (int idx = threadIdx.x; idx < 256 * 64; idx += 256) {
    int u = idx >> 6, d = idx & 63;
    u16 v = 0;
    if (u < krows) v = src[(size_t)(b * krows + u) * stride + coff + h * 64 + d];
    tile[d][u] = v;
  }
  __syncthreads();
  u16* dst = vT + (size_t)((b * 16 + h) * 64) * 256;
  for (int idx = threadIdx.x; idx < 64 * 256; idx += 256) {
    int d = idx >> 8, u = idx & 255;
    dst[(size_t)d * 256 + u] = tile[d][u];
  }
}

__global__ __launch_bounds__(256) void pv_kernel(
    const u16* __restrict__ P, const u16* __restrict__ vT, u16* __restrict__ O)
{
  int wid = blockIdx.x * 4 + (threadIdx.x >> 6);
  int lane = threadIdx.x & 63;
  int qt = wid % 13, h = (wid / 13) & 15, b = wid / 208;
  int lm = lane & 15, quad = lane >> 4;
  int t0 = qt * 16;
  int trow = t0 + lm; if (trow > 199) trow = 199;
  const u16* prow = P + ((size_t)((b * 16 + h) * 200) + trow) * 256;
  const u16* vbase = vT + (size_t)((b * 16 + h) * 64) * 256;
  floatx4 acc[4] = {};
  #pragma unroll
  for (int kb = 0; kb < 8; ++kb) {
    short8 a = ld8(prow + kb * 32 + quad * 8);
    #pragma unroll
    for (int dn = 0; dn < 4; ++dn) {
      short8 bb = ld8(vbase + (size_t)(dn * 16 + lm) * 256 + kb * 32 + quad * 8);
      acc[dn] = mfma16(a, bb, acc[dn]);
    }
  }
  #pragma unroll
  for (int dn = 0; dn < 4; ++dn)
    #pragma unroll
    for (int r = 0; r < 4; ++r) {
      int t = t0 + quad * 4 + r;
      if (t < 200)
        O[(size_t)(b * 200 + t) * 1024 + h * 64 + dn * 16 + lm] = f2bf(acc[dn][r]);
    }
}

// ---------------- LSTM prep (time-major lin rows = s*32+b) ----------------
__global__ void lstmin_kernel(const int* __restrict__ tgt, const float* __restrict__ ce,
                              const u16* __restrict__ cs, u16* __restrict__ out) {
  int row = blockIdx.x;
  int b = row / 1000, s = row - b * 1000;
  int c = threadIdx.x;
  u16 v;
  if (c < 128) {
    int id = (s == 0) ? 1 : tgt[b * 1000 + s - 1];
    v = f2bf(ce[id * 128 + c]);
  } else {
    v = cs[(size_t)row * 512 + (c - 128)];   // cs viewed as [32000,512]
  }
  out[(size_t)(s * 32 + b) * 640 + c] = v;
}

// ---------------- cooperative LSTM ----------------
DEV void gbar(unsigned* cnt, unsigned target) {
  __syncthreads();
  if (threadIdx.x == 0) {
    __threadfence();
    __hip_atomic_fetch_add(cnt, 1u, __ATOMIC_RELEASE, __HIP_MEMORY_SCOPE_AGENT);
    while (__hip_atomic_load(cnt, __ATOMIC_ACQUIRE, __HIP_MEMORY_SCOPE_AGENT) < target)
      __builtin_amdgcn_s_sleep(8);
    __threadfence();
  }
  __syncthreads();
}

__global__ __launch_bounds__(256, 1) void lstm_kernel(
    const u16* __restrict__ xproj, const u16* __restrict__ Wp,
    u16* __restrict__ hbuf, float* __restrict__ cbuf, u16* __restrict__ lout,
    unsigned* __restrict__ bar, int t0, int nsteps)
{
  __shared__ float gex[4][32][16];
  __shared__ float g2[32][16];
  int tid = threadIdx.x, lane = tid & 63, w = tid >> 6;
  int bk = blockIdx.x;
  int lm = lane & 15, quad = lane >> 4;
  int qbase = bk * 16;
  short8 wfrag[8];
  #pragma unroll
  for (int kk = 0; kk < 8; ++kk)
    wfrag[kk] = ld8(Wp + (size_t)(qbase + lm) * 1024 + (w * 8 + kk) * 32 + quad * 8);
  float c_reg = 0.f;
  if (tid < 128) {
    int u = tid >> 5, b = tid & 31;
    if (t0 == 0) {
      hbuf[b * 1024 + bk * 4 + u] = 0;
    } else {
      c_reg = cbuf[b * 1024 + bk * 4 + u];
    }
  }
  unsigned target = gridDim.x;
  gbar(bar, target);
  for (int tt = 0; tt < nsteps; ++tt) {
    int t = t0 + tt;
    const u16* hsrc = hbuf + (t & 1) * 32768;
    floatx4 acc0 = {0.f, 0.f, 0.f, 0.f}, acc1 = {0.f, 0.f, 0.f, 0.f};
    #pragma unroll
    for (int kk = 0; kk < 8; ++kk) {
      int k0 = (w * 8 + kk) * 32 + quad * 8;
      short8 a0 = ld8(hsrc + lm * 1024 + k0);
      short8 a1 = ld8(hsrc + (16 + lm) * 1024 + k0);
      acc0 = mfma16(a0, wfrag[kk], acc0);
      acc1 = mfma16(a1, wfrag[kk], acc1);
    }
    #pragma unroll
    for (int r = 0; r < 4; ++r) {
      gex[w][quad * 4 + r][lm] = acc0[r];
      gex[w][16 + quad * 4 + r][lm] = acc1[r];
    }
    __syncthreads();
    #pragma unroll
    for (int i = 0; i < 2; ++i) {
      int idx = tid + i * 256;
      int b = idx >> 4, qq = idx & 15;
      g2[b][qq] = gex[0][b][qq] + gex[1][b][qq] + gex[2][b][qq] + gex[3][b][qq]
                + bf2f(xproj[(size_t)(tt * 32 + b) * 4096 + qbase + qq]);
    }
    __syncthreads();
    if (tid < 128) {
      int u = tid >> 5, b = tid & 31;
      float gi = g2[b][u * 4 + 0];
      float gf = g2[b][u * 4 + 1];
      float gg = g2[b][u * 4 + 2];
      float go = g2[b][u * 4 + 3];
      c_reg = sigm(gf) * c_reg + sigm(gi) * tanhf(gg);
      float h = sigm(go) * tanhf(c_reg);
      u16 hb = f2bf(h);
      hbuf[((t + 1) & 1) * 32768 + b * 1024 + bk * 4 + u] = hb;
      lout[(size_t)(b * 1000 + t) * 1024 + bk * 4 + u] = hb;
    }
    target += gridDim.x;
    gbar(bar, target);
  }
  if (tid < 128) {
    int u = tid >> 5, b = tid & 31;
    cbuf[b * 1024 + bk * 4 + u] = c_reg;
  }
}

// ---------------- NLL ----------------
__global__ __launch_bounds__(256) void nll_kernel(
    const float* __restrict__ logits, const int* __restrict__ tgt,
    const float* __restrict__ tmask, float* __restrict__ acc)
{
  int wid = blockIdx.x * 4 + (threadIdx.x >> 6);
  int lane = threadIdx.x & 63;
  float ls = 0.f, ms = 0.f;
  for (int rr = 0; rr < 4; ++rr) {
    int row = wid * 4 + rr;
    const float* lp = logits + (size_t)row * 256;
    float v[4]; float mx = -3e38f;
    #pragma unroll
    for (int i = 0; i < 4; ++i) { v[i] = lp[lane + i * 64]; mx = fmaxf(mx, v[i]); }
    #pragma unroll
    for (int d = 1; d < 64; d <<= 1) mx = fmaxf(mx, __shfl_xor(mx, d, 64));
    float s = 0.f;
    #pragma unroll
    for (int i = 0; i < 4; ++i) s += __expf(v[i] - mx);
    #pragma unroll
    for (int d = 1; d < 64; d <<= 1) s += __shfl_xor(s, d, 64);
    float lse = mx + __logf(s);
    int tg = tgt[row];
    float tv = 0.f;
    #pragma unroll
    for (int i = 0; i < 4; ++i) if (lane + i * 64 == tg) tv = v[i];
    #pragma unroll
    for (int d = 1; d < 64; d <<= 1) tv += __shfl_xor(tv, d, 64);
    float mk = tmask[row];
    ls += (lse - tv) * mk;
    ms += mk;
  }
  if (lane == 0) { atomicAdd(&acc[0], ls); atomicAdd(&acc[1], ms); }
}

__global__ void zero_kernel(float* acc) {
  if (threadIdx.x == 0) { acc[0] = 0.f; acc[1] = 0.f; }
}
__global__ void bar_reset_kernel(unsigned* bar) {
  if (threadIdx.x == 0) *bar = 0u;
}
__global__ void finalize_kernel(const float* acc, float* out) {
  if (threadIdx.x == 0) out[0] = acc[0] / acc[1];
}
__global__ void diag_kernel(float* out, float v) {
  if (threadIdx.x == 0) out[0] = v;
}

// ---------------- workspace layout (bytes) ----------------
constexpr size_t AL(size_t x) { return (x + 255) & ~(size_t)255; }
constexpr size_t o_Wihp  = 0;
constexpr size_t o_Whhp  = AL(o_Wihp + 4096ull * 640 * 2);
constexpr size_t o_WoutT = AL(o_Whhp + 4096ull * 1024 * 2);
constexpr size_t o_bsum  = AL(o_WoutT + 256ull * 1536 * 2);
constexpr size_t o_hbuf  = AL(o_bsum + 4096ull * 4);
constexpr size_t o_cbuf  = AL(o_hbuf + 2ull * 32768 * 2);
constexpr size_t o_acc   = AL(o_cbuf + 32ull * 1024 * 4);
constexpr size_t o_smask = AL(o_acc + 256);
constexpr size_t o_cs    = AL(o_smask + 6400ull * 4);
constexpr size_t o_lout  = AL(o_cs + 6400ull * 2560 * 2);
constexpr size_t o_arena = AL(o_lout + 32000ull * 1024 * 2);
// phase A arena
constexpr size_t a_wl    = o_arena;
constexpr size_t wl_qkv  = a_wl;
constexpr size_t wl_wo   = wl_qkv + 3072ull * 1024 * 2;
constexpr size_t wl_cq   = wl_wo + 1024ull * 1024 * 2;
constexpr size_t wl_ckv  = wl_cq + 1024ull * 1024 * 2;
constexpr size_t wl_co   = wl_ckv + 2048ull * 1024 * 2;
constexpr size_t wl_w1   = wl_co + 1024ull * 1024 * 2;
constexpr size_t wl_w2   = wl_w1 + 2048ull * 1024 * 2;
constexpr size_t a_enc   = AL(wl_w2 + 2048ull * 1024 * 2);
constexpr size_t a_x     = AL(a_enc + 8192ull * 1024 * 2);
constexpr size_t a_xbf   = AL(a_x + 6400ull * 1024 * 4);
constexpr size_t a_scr   = AL(a_xbf + 6400ull * 1024 * 2);
constexpr size_t s_qkv   = a_scr;                       // 39.3MB; also qcr(13.1) + kv(33.6)
constexpr size_t s_kvc   = s_qkv + 6400ull * 1024 * 2;  // cross kv after qcr
constexpr size_t s_P     = AL(a_scr + 46661632ull);
constexpr size_t s_vT    = AL(s_P + 32ull * 16 * 200 * 256 * 2);
constexpr size_t s_S2    = AL(s_vT + 32ull * 16 * 64 * 256 * 2);   // attn | fbuf
constexpr size_t s_o32   = AL(s_S2 + 6400ull * 2048 * 2);
constexpr size_t a_endA  = AL(s_o32 + 6400ull * 1024 * 4);
// pre-layer aliases (inside scratch)
constexpr size_t s_emb   = a_scr;
constexpr size_t s_hbf   = a_scr + 32000ull * 128 * 2;
// phase B arena
constexpr size_t b_lin   = o_arena;
constexpr size_t b_xpj   = b_lin + 32000ull * 640 * 2;   // 131MB chunk; logits alias
constexpr size_t b_end   = AL(b_xpj + 16000ull * 4096 * 2);
constexpr size_t WS_NEED = (a_endA > b_end ? a_endA : b_end);

extern "C" void kernel_launch(void* const* d_in, const int* in_sizes, int n_in,
                              void* d_out, int out_size, void* d_ws, size_t ws_size,
                              hipStream_t stream)
{
  if (ws_size < WS_NEED) {
    // diagnostic: report workspace size (MB) through d_out so absmax reveals it
    diag_kernel<<<dim3(1), dim3(64), 0, stream>>>((float*)d_out, (float)(ws_size >> 20));
    return;
  }
  const float* enc     = (const float*)d_in[0];
  const float* encmask = (const float*)d_in[1];
  const int*   tgt     = (const int*)d_in[2];
  const float* tmask   = (const float*)d_in[3];
  const float* char_emb= (const float*)d_in[4];
  const float* pre_pos = (const float*)d_in[5];
  const float* Wc      = (const float*)d_in[6];
  const float* bc      = (const float*)d_in[7];
  const float* bert_pos= (const float*)d_in[8];
  const float* bert_tok= (const float*)d_in[9];
  const float* eln_g   = (const float*)d_in[10];
  const float* eln_b   = (const float*)d_in[11];
  const float* Wqkv    = (const float*)d_in[12];
  const float* bqkv    = (const float*)d_in[13];
  const float* Wo      = (const float*)d_in[14];
  const float* bo      = (const float*)d_in[15];
  const float* ln1g    = (const float*)d_in[16];
  const float* ln1b    = (const float*)d_in[17];
  const float* Cq      = (const float*)d_in[18];
  const float* cbq     = (const float*)d_in[19];
  const float* Ckv     = (const float*)d_in[20];
  const float* cbkv    = (const float*)d_in[21];
  const float* Co      = (const float*)d_in[22];
  const float* cbo     = (const float*)d_in[23];
  const float* ln2g    = (const float*)d_in[24];
  const float* ln2b    = (const float*)d_in[25];
  const float* W1      = (const float*)d_in[26];
  const float* b1      = (const float*)d_in[27];
  const float* W2      = (const float*)d_in[28];
  const float* b2      = (const float*)d_in[29];
  const float* ln3g    = (const float*)d_in[30];
  const float* ln3b    = (const float*)d_in[31];
  const float* Wnar    = (const float*)d_in[32];
  const float* bnar    = (const float*)d_in[33];
  const float* W_ih    = (const float*)d_in[34];
  const float* W_hh    = (const float*)d_in[35];
  const float* b_ih    = (const float*)d_in[36];
  const float* b_hh    = (const float*)d_in[37];
  const float* Wout    = (const float*)d_in[38];
  const float* bout    = (const float*)d_in[39];

  char* ws = (char*)d_ws;
  auto U = [&](size_t off) -> u16* { return (u16*)(ws + off); };
  auto F = [&](size_t off) -> float* { return (float*)(ws + off); };

  float* accum = F(o_acc);
  unsigned* barcnt = (unsigned*)(ws + o_acc + 8);
  zero_kernel<<<dim3(1), dim3(64), 0, stream>>>(accum);

  auto gemm = [&](const u16* A, const u16* BT, const float* bias, float* Cf, u16* Cb,
                  int M, int N, int K, int lda, int ldb, int ldc, int relu, int accf) {
    dim3 grid((M / 128) * (N / 128));
    if (Cb && relu)
      gemm_kernel<true, false, true, false><<<grid, 256, 0, stream>>>(A, BT, bias, nullptr, Cb, M, N, K, lda, ldb, ldc);
    else if (Cb)
      gemm_kernel<false, false, true, false><<<grid, 256, 0, stream>>>(A, BT, bias, nullptr, Cb, M, N, K, lda, ldb, ldc);
    else if (accf)
      gemm_kernel<false, true, false, true><<<grid, 256, 0, stream>>>(A, BT, bias, Cf, nullptr, M, N, K, lda, ldb, ldc);
    else
      gemm_kernel<false, true, false, false><<<grid, 256, 0, stream>>>(A, BT, bias, Cf, nullptr, M, N, K, lda, ldb, ldc);
  };

  // ---- persistent weight conversions ----
  cvt_perm_kernel<<<dim3(4096), 256, 0, stream>>>(W_ih, U(o_Wihp), 640);
  cvt_perm_kernel<<<dim3(4096), 256, 0, stream>>>(W_hh, U(o_Whhp), 1024);
  bias_perm_kernel<<<dim3(16), 256, 0, stream>>>(b_ih, b_hh, F(o_bsum));
  cvt_transpose_kernel<<<dim3(8, 48), 256, 0, stream>>>(Wout, U(o_WoutT), 1536, 256);
  cvt_kernel<<<dim3(4096), 256, 0, stream>>>(enc, U(a_enc), 32 * 256 * 1024);

  // ---- embedding + char->pseudoword (Wc into layer-weight slot) ----
  cvt_transpose_kernel<<<dim3(32, 4), 256, 0, stream>>>(Wc, U(a_wl), 128, 1024);
  embed_kernel<<<dim3(32000), dim3(128), 0, stream>>>(tgt, char_emb, pre_pos, U(s_emb));
  gemm(U(s_emb), U(a_wl), bc, nullptr, U(s_hbf), 32000, 1024, 128, 128, 128, 1024, 1, 0);
  pool_bert_ln_kernel<<<dim3(6400), 256, 0, stream>>>(
      U(s_hbf), tmask, bert_pos, bert_tok, eln_g, eln_b, F(a_x), U(a_xbf), F(o_smask));

  // ---- transformer layers (weights converted per layer into the slot) ----
  for (int l = 0; l < 6; ++l) {
    cvt_transpose_kernel<<<dim3(96, 32), 256, 0, stream>>>(Wqkv + (size_t)l * 1024 * 3072, U(wl_qkv), 1024, 3072);
    cvt_transpose_kernel<<<dim3(32, 32), 256, 0, stream>>>(Wo + (size_t)l * 1024 * 1024, U(wl_wo), 1024, 1024);
    cvt_transpose_kernel<<<dim3(32, 32), 256, 0, stream>>>(Cq + (size_t)l * 1024 * 1024, U(wl_cq), 1024, 1024);
    cvt_transpose_kernel<<<dim3(64, 32), 256, 0, stream>>>(Ckv + (size_t)l * 1024 * 2048, U(wl_ckv), 1024, 2048);
    cvt_transpose_kernel<<<dim3(32, 32), 256, 0, stream>>>(Co + (size_t)l * 1024 * 1024, U(wl_co), 1024, 1024);
    cvt_transpose_kernel<<<dim3(64, 32), 256, 0, stream>>>(W1 + (size_t)l * 1024 * 2048, U(wl_w1), 1024, 2048);
    cvt_transpose_kernel<<<dim3(32, 64), 256, 0, stream>>>(W2 + (size_t)l * 2048 * 1024, U(wl_w2), 2048, 1024);

    // self-attention
    gemm(U(a_xbf), U(wl_qkv), bqkv + l * 3072, nullptr, U(s_qkv), 6400, 3072, 1024, 1024, 1024, 3072, 0, 0);
    vtrans_kernel<<<dim3(512), 256, 0, stream>>>(U(s_qkv), 3072, 2048, 200, U(s_vT));
    scores_kernel<<<dim3(1664), 256, 0, stream>>>(
        U(s_qkv), 3072, U(s_qkv), 3072, 1024, 200, F(o_smask), U(s_P), 1);
    pv_kernel<<<dim3(1664), 256, 0, stream>>>(U(s_P), U(s_vT), U(s_S2));
    gemm(U(s_S2), U(wl_wo), bo + l * 1024, F(s_o32), nullptr, 6400, 1024, 1024, 1024, 1024, 1024, 0, 0);
    resid_ln_kernel<<<dim3(6400), 256, 0, stream>>>(F(a_x), F(s_o32), ln1g + l * 1024, ln1b + l * 1024, U(a_xbf));

    // cross-attention
    gemm(U(a_xbf), U(wl_cq), cbq + l * 1024, nullptr, U(s_qkv), 6400, 1024, 1024, 1024, 1024, 1024, 0, 0);
    gemm(U(a_enc), U(wl_ckv), cbkv + l * 2048, nullptr, U(s_kvc), 8192, 2048, 1024, 1024, 1024, 2048, 0, 0);
    vtrans_kernel<<<dim3(512), 256, 0, stream>>>(U(s_kvc), 2048, 1024, 256, U(s_vT));
    scores_kernel<<<dim3(1664), 256, 0, stream>>>(
        U(s_qkv), 1024, U(s_kvc), 2048, 0, 256, encmask, U(s_P), 0);
    pv_kernel<<<dim3(1664), 256, 0, stream>>>(U(s_P), U(s_vT), U(s_S2));
    gemm(U(s_S2), U(wl_co), cbo + l * 1024, F(s_o32), nullptr, 6400, 1024, 1024, 1024, 1024, 1024, 0, 0);
    resid_ln_kernel<<<dim3(6400), 256, 0, stream>>>(F(a_x), F(s_o32), ln2g + l * 1024, ln2b + l * 1024, U(a_xbf));

    // FFN
    gemm(U(a_xbf), U(wl_w1), b1 + l * 2048, nullptr, U(s_S2), 6400, 2048, 1024, 1024, 1024, 2048, 1, 0);
    gemm(U(s_S2), U(wl_w2), b2 + l * 1024, F(s_o32), nullptr, 6400, 1024, 2048, 2048, 2048, 1024, 0, 0);
    resid_ln_kernel<<<dim3(6400), 256, 0, stream>>>(F(a_x), F(s_o32), ln3g + l * 1024, ln3b + l * 1024, U(a_xbf));
  }

  // ---- nar proj -> char states (persistent cs) ----
  cvt_transpose_kernel<<<dim3(80, 32), 256, 0, stream>>>(Wnar, U(a_wl), 1024, 2560);
  gemm(U(a_xbf), U(a_wl), bnar, nullptr, U(o_cs), 6400, 2560, 1024, 1024, 1024, 2560, 0, 0);

  // ---- LSTM input (time-major) ----
  lstmin_kernel<<<dim3(32000), dim3(640), 0, stream>>>(tgt, char_emb, U(o_cs), U(b_lin));

  // ---- chunked xproj GEMM + cooperative LSTM ----
  for (int c = 0; c < 2; ++c) {
    gemm(U(b_lin) + (size_t)c * 16000 * 640, U(o_Wihp), F(o_bsum), nullptr, U(b_xpj),
         16000, 4096, 640, 640, 640, 4096, 0, 0);
    bar_reset_kernel<<<dim3(1), dim3(64), 0, stream>>>(barcnt);
    const u16* xprojp = U(b_xpj);
    const u16* Wpp = U(o_Whhp);
    u16* hbufp = U(o_hbuf);
    float* cbufp = F(o_cbuf);
    u16* loutp = U(o_lout);
    unsigned* barp = barcnt;
    int t0 = c * 500, ns = 500;
    void* kargs[] = { &xprojp, &Wpp, &hbufp, &cbufp, &loutp, &barp, &t0, &ns };
    hipLaunchCooperativeKernel(lstm_kernel, dim3(256), dim3(256), kargs, 0u, stream);
  }

  // ---- output projection (split concat) + NLL ----
  gemm(U(o_lout), U(o_WoutT), bout, F(b_xpj), nullptr, 32000, 256, 1024, 1024, 1536, 256, 0, 0);
  gemm(U(o_cs), U(o_WoutT) + 1024, nullptr, F(b_xpj), nullptr, 32000, 256, 512, 512, 1536, 256, 0, 1);
  nll_kernel<<<dim3(2000), 256, 0, stream>>>(F(b_xpj), tgt, tmask, accum);
  finalize_kernel<<<dim3(1), dim3(64), 0, stream>>>(accum, (float*)d_out);
}

// Round 3
// 14680.383 us; speedup vs baseline: 2.5491x; 2.5491x over previous
//
#include <hip/hip_runtime.h>
#include <cstdint>
#include <cstddef>

#define DEV __device__ __forceinline__

typedef unsigned short u16;
typedef __attribute__((ext_vector_type(8))) short short8;
typedef __attribute__((ext_vector_type(4))) float floatx4;

DEV float bf2f(u16 h) { union { unsigned u; float f; } c; c.u = ((unsigned)h) << 16; return c.f; }
DEV u16 f2bf(float f) {
  union { float f; unsigned u; } c; c.f = f;
  unsigned r = 0x7fffu + ((c.u >> 16) & 1u);
  return (u16)((c.u + r) >> 16);
}
DEV short8 ld8(const u16* p) { return *(const short8*)p; }
DEV floatx4 mfma16(short8 a, short8 b, floatx4 c) {
  return __builtin_amdgcn_mfma_f32_16x16x32_bf16(a, b, c, 0, 0, 0);
}
DEV void async16(const u16* g, u16* l) {
  __builtin_amdgcn_global_load_lds((__attribute__((address_space(1))) void*)(uintptr_t)(const void*)g,
                                   (__attribute__((address_space(3))) void*)(uintptr_t)(void*)l, 16, 0, 0);
}
DEV float sigm(float x) { return 1.f / (1.f + __expf(-x)); }

DEV float blk_sum256(float v) {
  __shared__ float sh[4];
  #pragma unroll
  for (int d = 32; d >= 1; d >>= 1) v += __shfl_xor(v, d, 64);
  if ((threadIdx.x & 63) == 0) sh[threadIdx.x >> 6] = v;
  __syncthreads();
  v = sh[0] + sh[1] + sh[2] + sh[3];
  __syncthreads();
  return v;
}

// ---------------- generic bf16 MFMA GEMM: C = A[M,K] * BT[N,K]^T (+bias) ----------------
template<bool RELU, bool WF32, bool WBF16, bool ACC>
__global__ __launch_bounds__(256, 2) void gemm_kernel(
    const u16* __restrict__ A, const u16* __restrict__ BT,
    const float* __restrict__ bias, float* __restrict__ Cf, u16* __restrict__ Cb,
    int M, int N, int K, int lda, int ldb, int ldc)
{
  __shared__ u16 As[4096];
  __shared__ u16 Bs[4096];
  const int tid = threadIdx.x;
  const int lane = tid & 63;
  const int w = tid >> 6;
  const int nTiles = N >> 7;
  const int bm = blockIdx.x / nTiles;
  const int bn = blockIdx.x - bm * nTiles;
  const int m0 = bm << 7, n0 = bn << 7;
  const int q = lane >> 4, lm = lane & 15;
  const int wm = (w & 1) << 6, wn = (w >> 1) << 6;

  const int s1 = tid, s2 = tid + 256;
  const int r1 = s1 >> 2, c1 = (s1 & 3) ^ ((r1 >> 2) & 3);
  const int r2 = s2 >> 2, c2 = (s2 & 3) ^ ((r2 >> 2) & 3);
  const u16* ga1 = A + (size_t)(m0 + r1) * lda + c1 * 8;
  const u16* ga2 = A + (size_t)(m0 + r2) * lda + c2 * 8;
  const u16* gb1 = BT + (size_t)(n0 + r1) * ldb + c1 * 8;
  const u16* gb2 = BT + (size_t)(n0 + r2) * ldb + c2 * 8;

  floatx4 acc[4][4] = {};

  for (int kt = 0; kt < K; kt += 32) {
    async16(ga1 + kt, &As[s1 * 8]);
    async16(ga2 + kt, &As[s2 * 8]);
    async16(gb1 + kt, &Bs[s1 * 8]);
    async16(gb2 + kt, &Bs[s2 * 8]);
    __syncthreads();
    short8 af[4], bfr[4];
    #pragma unroll
    for (int i = 0; i < 4; ++i) {
      int r = wm + i * 16 + lm;
      af[i] = ld8(&As[(r * 4 + (q ^ ((r >> 2) & 3))) * 8]);
      r = wn + i * 16 + lm;
      bfr[i] = ld8(&Bs[(r * 4 + (q ^ ((r >> 2) & 3))) * 8]);
    }
    #pragma unroll
    for (int mi = 0; mi < 4; ++mi)
      #pragma unroll
      for (int ni = 0; ni < 4; ++ni)
        acc[mi][ni] = mfma16(af[mi], bfr[ni], acc[mi][ni]);
    __syncthreads();
  }
  #pragma unroll
  for (int ni = 0; ni < 4; ++ni) {
    int col = n0 + wn + ni * 16 + lm;
    float bv = ACC ? 0.f : bias[col];
    #pragma unroll
    for (int mi = 0; mi < 4; ++mi) {
      int rowb = m0 + wm + mi * 16 + q * 4;
      #pragma unroll
      for (int r = 0; r < 4; ++r) {
        float v = acc[mi][ni][r] + bv;
        if (RELU) v = fmaxf(v, 0.f);
        size_t idx = (size_t)(rowb + r) * ldc + col;
        if (WF32) { if (ACC) Cf[idx] += v; else Cf[idx] = v; }
        if (WBF16) Cb[idx] = f2bf(v);
      }
    }
  }
}

// ---------------- weight conversion kernels ----------------
__global__ __launch_bounds__(256) void cvt_transpose_kernel(
    const float* __restrict__ src, u16* __restrict__ dst, int K, int N)
{
  __shared__ float tile[32][33];
  int n0 = blockIdx.x * 32, k0 = blockIdx.y * 32;
  int tx = threadIdx.x & 31, ty = threadIdx.x >> 5;
  #pragma unroll
  for (int i = 0; i < 32; i += 8)
    tile[ty + i][tx] = src[(size_t)(k0 + ty + i) * N + n0 + tx];
  __syncthreads();
  #pragma unroll
  for (int i = 0; i < 32; i += 8)
    dst[(size_t)(n0 + ty + i) * K + k0 + tx] = f2bf(tile[tx][ty + i]);
}

__global__ void cvt_kernel(const float* __restrict__ s, u16* __restrict__ d, int n) {
  int i = blockIdx.x * 256 + threadIdx.x;
  int stride = gridDim.x * 256;
  for (; i < n; i += stride) d[i] = f2bf(s[i]);
}

// permute gate rows: dst row q <- src row (q&3)*1024 + (q>>2)
__global__ void cvt_perm_kernel(const float* __restrict__ src, u16* __restrict__ dst, int cols) {
  int qrow = blockIdx.x;
  int orig = (qrow & 3) * 1024 + (qrow >> 2);
  const float* sp = src + (size_t)orig * cols;
  u16* dp = dst + (size_t)qrow * cols;
  for (int c = threadIdx.x; c < cols; c += 256) dp[c] = f2bf(sp[c]);
}

__global__ void bias_perm_kernel(const float* __restrict__ bih, const float* __restrict__ bhh,
                                 float* __restrict__ bsum) {
  int q = blockIdx.x * 256 + threadIdx.x;
  int orig = (q & 3) * 1024 + (q >> 2);
  bsum[q] = bih[orig] + bhh[orig];
}

// ---------------- embedding / pooling / LN ----------------
__global__ void embed_kernel(const int* __restrict__ tgt, const float* __restrict__ ce,
                             const float* __restrict__ pp, u16* __restrict__ out) {
  int row = blockIdx.x;
  int b = row / 1000, s = row - b * 1000;
  int id = (s < 5) ? 1 : tgt[b * 1000 + s - 5];
  int e = threadIdx.x;
  out[(size_t)row * 128 + e] = f2bf(ce[id * 128 + e] + pp[s * 128 + e]);
}

__global__ __launch_bounds__(256) void pool_bert_ln_kernel(
    const u16* __restrict__ hb, const float* __restrict__ tmask,
    const float* __restrict__ pos, const float* __restrict__ tok,
    const float* __restrict__ g, const float* __restrict__ bt,
    float* __restrict__ x, u16* __restrict__ xb, float* __restrict__ smaskOut)
{
  int row = blockIdx.x, b = row / 200, t = row - b * 200;
  int tid = threadIdx.x;
  float m[4] = {0.f, 0.f, 0.f, 0.f};
  float sm = 0.f;
  for (int wi = 0; wi < 5; ++wi) {
    int s = t * 5 + wi;
    float im = (s < 5) ? 1.f : tmask[b * 1000 + s - 5];
    sm = fmaxf(sm, im);
    const u16* hr = hb + (size_t)(b * 1000 + s) * 1024;
    #pragma unroll
    for (int i = 0; i < 4; ++i) {
      int d = tid + i * 256;
      m[i] = fmaxf(m[i], bf2f(hr[d]) * im);
    }
  }
  float y[4]; float ssum = 0.f;
  #pragma unroll
  for (int i = 0; i < 4; ++i) {
    int d = tid + i * 256;
    y[i] = m[i] + pos[t * 1024 + d] + tok[d];
    ssum += y[i];
  }
  float mean = blk_sum256(ssum) * (1.f / 1024.f);
  float vs = 0.f;
  #pragma unroll
  for (int i = 0; i < 4; ++i) { float dd = y[i] - mean; vs += dd * dd; }
  float var = blk_sum256(vs) * (1.f / 1024.f);
  float rs = rsqrtf(var + 1e-12f);
  #pragma unroll
  for (int i = 0; i < 4; ++i) {
    int d = tid + i * 256;
    float o = (y[i] - mean) * rs * g[d] + bt[d];
    x[(size_t)row * 1024 + d] = o;
    xb[(size_t)row * 1024 + d] = f2bf(o);
  }
  if (tid == 0) smaskOut[row] = sm;
}

__global__ __launch_bounds__(256) void resid_ln_kernel(
    float* __restrict__ x, const float* __restrict__ o,
    const float* __restrict__ g, const float* __restrict__ bt,
    u16* __restrict__ xb)
{
  size_t row = blockIdx.x;
  int tid = threadIdx.x;
  float y[4]; float s = 0.f;
  #pragma unroll
  for (int i = 0; i < 4; ++i) {
    int d = tid + i * 256;
    y[i] = x[row * 1024 + d] + o[row * 1024 + d];
    s += y[i];
  }
  float mean = blk_sum256(s) * (1.f / 1024.f);
  float vs = 0.f;
  #pragma unroll
  for (int i = 0; i < 4; ++i) { float dd = y[i] - mean; vs += dd * dd; }
  float var = blk_sum256(vs) * (1.f / 1024.f);
  float rs = rsqrtf(var + 1e-12f);
  #pragma unroll
  for (int i = 0; i < 4; ++i) {
    int d = tid + i * 256;
    float out = (y[i] - mean) * rs * g[d] + bt[d];
    x[row * 1024 + d] = out;
    xb[row * 1024 + d] = f2bf(out);
  }
}

// ---------------- attention: fused QK^T + softmax -> P (bf16) ----------------
__global__ __launch_bounds__(256) void scores_kernel(
    const u16* __restrict__ Q, int qstride,
    const u16* __restrict__ Kp, int kstride, int kcoff, int krows,
    const float* __restrict__ mask, u16* __restrict__ P, int selfmode)
{
  int wid = blockIdx.x * 4 + (threadIdx.x >> 6);
  int lane = threadIdx.x & 63;
  int qt = wid % 13, h = (wid / 13) & 15, b = wid / 208;
  int lm = lane & 15, quad = lane >> 4;
  int t0 = qt * 16;
  int trow = t0 + lm; if (trow > 199) trow = 199;
  const u16* qp = Q + (size_t)(b * 200 + trow) * qstride + h * 64;
  short8 a0 = ld8(qp + quad * 8);
  short8 a1 = ld8(qp + 32 + quad * 8);
  floatx4 S[16];
  const int nmf = selfmode ? 13 : 16;
  for (int ut = 0; ut < nmf; ++ut) {
    int ur = ut * 16 + lm; if (ur >= krows) ur = krows - 1;
    const u16* kp = Kp + (size_t)(b * krows + ur) * kstride + kcoff + h * 64;
    floatx4 z = {0.f, 0.f, 0.f, 0.f};
    z = mfma16(a0, ld8(kp + quad * 8), z);
    z = mfma16(a1, ld8(kp + 32 + quad * 8), z);
    S[ut] = z;
  }
  for (int ut = nmf; ut < 16; ++ut) S[ut] = (floatx4){0.f, 0.f, 0.f, 0.f};
  const float scale = 0.125f;
  u16* prow_base = P + (size_t)((b * 16 + h) * 200) * 256;
  for (int r = 0; r < 4; ++r) {
    int t = t0 + quad * 4 + r;
    float mx = -3e38f;
    float vv[16];
    #pragma unroll
    for (int ut = 0; ut < 16; ++ut) {
      int u = ut * 16 + lm;
      float bias;
      if (selfmode) {
        bias = ((u <= t && u < 200) ? 0.f : -1e9f);
        if (u < 200) bias += (1.f - mask[b * 200 + u]) * -1e9f;
      } else {
        bias = (1.f - mask[b * 256 + u]) * -1e9f;
      }
      float v = S[ut][r] * scale + bias;
      vv[ut] = v;
      mx = fmaxf(mx, v);
    }
    #pragma unroll
    for (int d = 1; d < 16; d <<= 1) mx = fmaxf(mx, __shfl_xor(mx, d, 64));
    float sum = 0.f;
    #pragma unroll
    for (int ut = 0; ut < 16; ++ut) { float e = __expf(vv[ut] - mx); vv[ut] = e; sum += e; }
    #pragma unroll
    for (int d = 1; d < 16; d <<= 1) sum += __shfl_xor(sum, d, 64);
    float inv = 1.f / sum;
    if (t < 200) {
      u16* pr = prow_base + (size_t)t * 256;
      #pragma unroll
      for (int ut = 0; ut < 16; ++ut) pr[ut * 16 + lm] = f2bf(vv[ut] * inv);
    }
  }
}

// transpose V slice -> vT[b,h,64,256]
__global__ __launch_bounds__(256) void vtrans_kernel(
    const u16* __restrict__ src, int stride, int coff, int krows, u16* __restrict__ vT)
{
  int b = blockIdx.x >> 4, h = blockIdx.x & 15;
  __shared__ u16 tile[64][257];
  for (int idx = threadIdx.x; idx < 256 * 64; idx += 256) {
    int u = idx >> 6, d = idx & 63;
    u16 v = 0;
    if (u < krows) v = src[(size_t)(b * krows + u) * stride + coff + h * 64 + d];
    tile[d][u] = v;
  }
  __syncthreads();
  u16* dst = vT + (size_t)((b * 16 + h) * 64) * 256;
  for (int idx = threadIdx.x; idx < 64 * 256; idx += 256) {
    int d = idx >> 8, u = idx & 255;
    dst[(size_t)d * 256 + u] = tile[d][u];
  }
}

__global__ __launch_bounds__(256) void pv_kernel(
    const u16* __restrict__ P, const u16* __restrict__ vT, u16* __restrict__ O)
{
  int wid = blockIdx.x * 4 + (threadIdx.x >> 6);
  int lane = threadIdx.x & 63;
  int qt = wid % 13, h = (wid / 13) & 15, b = wid / 208;
  int lm = lane & 15, quad = lane >> 4;
  int t0 = qt * 16;
  int trow = t0 + lm; if (trow > 199) trow = 199;
  const u16* prow = P + ((size_t)((b * 16 + h) * 200) + trow) * 256;
  const u16* vbase = vT + (size_t)((b * 16 + h) * 64) * 256;
  floatx4 acc[4] = {};
  #pragma unroll
  for (int kb = 0; kb < 8; ++kb) {
    short8 a = ld8(prow + kb * 32 + quad * 8);
    #pragma unroll
    for (int dn = 0; dn < 4; ++dn) {
      short8 bb = ld8(vbase + (size_t)(dn * 16 + lm) * 256 + kb * 32 + quad * 8);
      acc[dn] = mfma16(a, bb, acc[dn]);
    }
  }
  #pragma unroll
  for (int dn = 0; dn < 4; ++dn)
    #pragma unroll
    for (int r = 0; r < 4; ++r) {
      int t = t0 + quad * 4 + r;
      if (t < 200)
        O[(size_t)(b * 200 + t) * 1024 + h * 64 + dn * 16 + lm] = f2bf(acc[dn][r]);
    }
}

// ---------------- LSTM prep (time-major lin rows = s*32+b) ----------------
__global__ void lstmin_kernel(const int* __restrict__ tgt, const float* __restrict__ ce,
                              const u16* __restrict__ cs, u16* __restrict__ out) {
  int row = blockIdx.x;
  int b = row / 1000, s = row - b * 1000;
  int c = threadIdx.x;
  u16 v;
  if (c < 128) {
    int id = (s == 0) ? 1 : tgt[b * 1000 + s - 1];
    v = f2bf(ce[id * 128 + c]);
  } else {
    v = cs[(size_t)row * 512 + (c - 128)];   // cs viewed as [32000,512]
  }
  out[(size_t)(s * 32 + b) * 640 + c] = v;
}

// ---------------- LSTM: 64 blocks, flag-array device barrier (no atomic RMW) ----------------
// h state global layout: h_pad[2][32][2048] bf16 — block bk owns cols [bk*32, bk*32+16)
// of each row => every (b,bk) 32-B segment lives in exactly one 64-B line (no false sharing).
__global__ __launch_bounds__(256, 1) void lstm_kernel(
    const u16* __restrict__ xproj, const u16* __restrict__ Wp,
    u16* __restrict__ hbuf, float* __restrict__ cbuf, u16* __restrict__ lout,
    unsigned* __restrict__ flags, int t0, int nsteps)
{
  __shared__ u16 smem[32768];            // 64 KB: h staging (bf16), aliased as f32 gate buffer
  float* g_all = (float*)smem;           // [32][66] after re-sync

  const int tid = threadIdx.x;
  const int lane = tid & 63;
  const int w = tid >> 6;
  const int bk = blockIdx.x;             // 64 blocks x 64 gate cols
  const int lm = lane & 15, quad = lane >> 4;
  const int Q0 = bk * 64;

  // full-K weight fragments for this wave's 16 gate cols (128 VGPRs)
  short8 wfrag[32];
  #pragma unroll
  for (int kk = 0; kk < 32; ++kk)
    wfrag[kk] = ld8(Wp + (size_t)(Q0 + w * 16 + lm) * 1024 + kk * 32 + quad * 8);

  const int b_ = tid >> 3;               // batch row 0..31
  const int u0 = (tid & 7) * 2;          // 2 hidden units per thread (of block's 16)
  float c0 = 0.f, c1 = 0.f;
  if (t0 == 0) {
    *(unsigned*)&hbuf[b_ * 2048 + bk * 32 + u0] = 0u;   // zero h[0] slice (2 bf16)
  } else {
    c0 = cbuf[b_ * 1024 + bk * 16 + u0];
    c1 = cbuf[b_ * 1024 + bk * 16 + u0 + 1];
  }
  __syncthreads();
  if (w == 0) {
    __builtin_amdgcn_fence(__ATOMIC_RELEASE, "agent");
    if (lane == 0)
      __hip_atomic_store(&flags[bk * 16], 1u, __ATOMIC_RELAXED, __HIP_MEMORY_SCOPE_AGENT);
  }

  for (int ltt = 0; ltt < nsteps; ++ltt) {
    const int t = t0 + ltt;

    // prefetch this step's xproj fragment (independent of h) before the wait
    short8 xp = ld8(xproj + (size_t)(ltt * 32 + b_) * 4096 + Q0 + u0 * 4);

    // ---- wait for all 64 blocks to have posted step ltt ----
    if (w == 0) {
      unsigned want = (unsigned)(ltt + 1);
      int spin = 0;
      for (;;) {
        unsigned v = __hip_atomic_load(&flags[lane * 16], __ATOMIC_RELAXED, __HIP_MEMORY_SCOPE_AGENT);
        if (__all((int)(v >= want))) break;
        if (((++spin) & 63) == 0) __builtin_amdgcn_fence(__ATOMIC_ACQUIRE, "agent");
        __builtin_amdgcn_s_sleep(1);
      }
      __builtin_amdgcn_fence(__ATOMIC_ACQUIRE, "agent");
    }
    __syncthreads();

    // ---- stage h[32][1024] into LDS (xor-swizzled for conflict-free b128 reads) ----
    const u16* hsrc = hbuf + (size_t)(t & 1) * 65536;
    #pragma unroll
    for (int it = 0; it < 16; ++it) {
      int i = it * 2048 + tid * 8;
      int b = i >> 10, c = i & 1023;
      short8 v = ld8(hsrc + b * 2048 + ((c >> 4) << 5) + (c & 15));
      *(short8*)&smem[b * 1024 + (c ^ ((b & 7) * 8))] = v;
    }
    __syncthreads();

    // ---- gates = h @ Wp^T (this block's 64 cols; each wave full K) ----
    floatx4 acc0 = {0.f, 0.f, 0.f, 0.f}, acc1 = {0.f, 0.f, 0.f, 0.f};
    #pragma unroll
    for (int kk = 0; kk < 32; ++kk) {
      int cix = kk * 32 + quad * 8;
      short8 a0 = ld8(&smem[lm * 1024 + (cix ^ ((lm & 7) * 8))]);
      short8 a1 = ld8(&smem[(16 + lm) * 1024 + (cix ^ ((lm & 7) * 8))]);
      acc0 = mfma16(a0, wfrag[kk], acc0);
      acc1 = mfma16(a1, wfrag[kk], acc1);
    }
    __syncthreads();                      // all hs reads done before aliased dump
    #pragma unroll
    for (int r = 0; r < 4; ++r) {
      g_all[(quad * 4 + r) * 66 + w * 16 + lm] = acc0[r];
      g_all[(16 + quad * 4 + r) * 66 + w * 16 + lm] = acc1[r];
    }
    __syncthreads();

    // ---- nonlinearity: 2 hidden units per thread ----
    const u16* xpp = (const u16*)&xp;
    const float* gb = g_all + b_ * 66 + u0 * 4;
    float gi = gb[0] + bf2f(xpp[0]);
    float gf = gb[1] + bf2f(xpp[1]);
    float gg = gb[2] + bf2f(xpp[2]);
    float go = gb[3] + bf2f(xpp[3]);
    c0 = sigm(gf) * c0 + sigm(gi) * tanhf(gg);
    float h0v = sigm(go) * tanhf(c0);
    gi = gb[4] + bf2f(xpp[4]);
    gf = gb[5] + bf2f(xpp[5]);
    gg = gb[6] + bf2f(xpp[6]);
    go = gb[7] + bf2f(xpp[7]);
    c1 = sigm(gf) * c1 + sigm(gi) * tanhf(gg);
    float h1v = sigm(go) * tanhf(c1);

    u16* hdst = hbuf + (size_t)((t + 1) & 1) * 65536 + b_ * 2048 + bk * 32 + u0;
    hdst[0] = f2bf(h0v);
    hdst[1] = f2bf(h1v);
    u16* lo = lout + (size_t)(b_ * 1000 + t) * 1024 + bk * 16 + u0;
    lo[0] = f2bf(h0v);
    lo[1] = f2bf(h1v);

    __syncthreads();                      // drain all h stores to L2
    if (w == 0) {
      __builtin_amdgcn_fence(__ATOMIC_RELEASE, "agent");
      if (lane == 0)
        __hip_atomic_store(&flags[bk * 16], (unsigned)(ltt + 2), __ATOMIC_RELAXED, __HIP_MEMORY_SCOPE_AGENT);
    }
  }
  cbuf[b_ * 1024 + bk * 16 + u0] = c0;
  cbuf[b_ * 1024 + bk * 16 + u0 + 1] = c1;
}

// ---------------- NLL ----------------
__global__ __launch_bounds__(256) void nll_kernel(
    const float* __restrict__ logits, const int* __restrict__ tgt,
    const float* __restrict__ tmask, float* __restrict__ acc)
{
  int wid = blockIdx.x * 4 + (threadIdx.x >> 6);
  int lane = threadIdx.x & 63;
  float ls = 0.f, ms = 0.f;
  for (int rr = 0; rr < 4; ++rr) {
    int row = wid * 4 + rr;
    const float* lp = logits + (size_t)row * 256;
    float v[4]; float mx = -3e38f;
    #pragma unroll
    for (int i = 0; i < 4; ++i) { v[i] = lp[lane + i * 64]; mx = fmaxf(mx, v[i]); }
    #pragma unroll
    for (int d = 1; d < 64; d <<= 1) mx = fmaxf(mx, __shfl_xor(mx, d, 64));
    float s = 0.f;
    #pragma unroll
    for (int i = 0; i < 4; ++i) s += __expf(v[i] - mx);
    #pragma unroll
    for (int d = 1; d < 64; d <<= 1) s += __shfl_xor(s, d, 64);
    float lse = mx + __logf(s);
    int tg = tgt[row];
    float tv = 0.f;
    #pragma unroll
    for (int i = 0; i < 4; ++i) if (lane + i * 64 == tg) tv = v[i];
    #pragma unroll
    for (int d = 1; d < 64; d <<= 1) tv += __shfl_xor(tv, d, 64);
    float mk = tmask[row];
    ls += (lse - tv) * mk;
    ms += mk;
  }
  if (lane == 0) { atomicAdd(&acc[0], ls); atomicAdd(&acc[1], ms); }
}

__global__ void zero_kernel(float* acc) {
  if (threadIdx.x == 0) { acc[0] = 0.f; acc[1] = 0.f; }
}
__global__ void flags_reset_kernel(unsigned* flags) {
  int i = threadIdx.x;
  #pragma unroll
  for (int k = 0; k < 4; ++k) flags[i + k * 256] = 0u;
}
__global__ void finalize_kernel(const float* acc, float* out) {
  if (threadIdx.x == 0) out[0] = acc[0] / acc[1];
}
__global__ void diag_kernel(float* out, float v) {
  if (threadIdx.x == 0) out[0] = v;
}

// ---------------- workspace layout (bytes) ----------------
constexpr size_t AL(size_t x) { return (x + 255) & ~(size_t)255; }
constexpr size_t o_Wihp  = 0;
constexpr size_t o_Whhp  = AL(o_Wihp + 4096ull * 640 * 2);
constexpr size_t o_WoutT = AL(o_Whhp + 4096ull * 1024 * 2);
constexpr size_t o_bsum  = AL(o_WoutT + 256ull * 1536 * 2);
constexpr size_t o_hbuf  = AL(o_bsum + 4096ull * 4);
constexpr size_t o_cbuf  = AL(o_hbuf + 2ull * 32 * 2048 * 2);
constexpr size_t o_acc   = AL(o_cbuf + 32ull * 1024 * 4);
constexpr size_t o_flags = AL(o_acc + 256);
constexpr size_t o_smask = AL(o_flags + 4096);
constexpr size_t o_cs    = AL(o_smask + 6400ull * 4);
constexpr size_t o_lout  = AL(o_cs + 6400ull * 2560 * 2);
constexpr size_t o_arena = AL(o_lout + 32000ull * 1024 * 2);
// phase A arena
constexpr size_t a_wl    = o_arena;
constexpr size_t wl_qkv  = a_wl;
constexpr size_t wl_wo   = wl_qkv + 3072ull * 1024 * 2;
constexpr size_t wl_cq   = wl_wo + 1024ull * 1024 * 2;
constexpr size_t wl_ckv  = wl_cq + 1024ull * 1024 * 2;
constexpr size_t wl_co   = wl_ckv + 2048ull * 1024 * 2;
constexpr size_t wl_w1   = wl_co + 1024ull * 1024 * 2;
constexpr size_t wl_w2   = wl_w1 + 2048ull * 1024 * 2;
constexpr size_t a_enc   = AL(wl_w2 + 2048ull * 1024 * 2);
constexpr size_t a_x     = AL(a_enc + 8192ull * 1024 * 2);
constexpr size_t a_xbf   = AL(a_x + 6400ull * 1024 * 4);
constexpr size_t a_scr   = AL(a_xbf + 6400ull * 1024 * 2);
constexpr size_t s_qkv   = a_scr;                       // 39.3MB; also qcr(13.1) + kv(33.6)
constexpr size_t s_kvc   = s_qkv + 6400ull * 1024 * 2;  // cross kv after qcr
constexpr size_t s_P     = AL(a_scr + 46661632ull);
constexpr size_t s_vT    = AL(s_P + 32ull * 16 * 200 * 256 * 2);
constexpr size_t s_S2    = AL(s_vT + 32ull * 16 * 64 * 256 * 2);   // attn | fbuf
constexpr size_t s_o32   = AL(s_S2 + 6400ull * 2048 * 2);
constexpr size_t a_endA  = AL(s_o32 + 6400ull * 1024 * 4);
// pre-layer aliases (inside scratch)
constexpr size_t s_emb   = a_scr;
constexpr size_t s_hbf   = a_scr + 32000ull * 128 * 2;
// phase B arena
constexpr size_t b_lin   = o_arena;
constexpr size_t b_xpj   = b_lin + 32000ull * 640 * 2;   // 131MB chunk; logits alias
constexpr size_t b_end   = AL(b_xpj + 16000ull * 4096 * 2);
constexpr size_t WS_NEED = (a_endA > b_end ? a_endA : b_end);

extern "C" void kernel_launch(void* const* d_in, const int* in_sizes, int n_in,
                              void* d_out, int out_size, void* d_ws, size_t ws_size,
                              hipStream_t stream)
{
  if (ws_size < WS_NEED) {
    diag_kernel<<<dim3(1), dim3(64), 0, stream>>>((float*)d_out, (float)(ws_size >> 20));
    return;
  }
  const float* enc     = (const float*)d_in[0];
  const float* encmask = (const float*)d_in[1];
  const int*   tgt     = (const int*)d_in[2];
  const float* tmask   = (const float*)d_in[3];
  const float* char_emb= (const float*)d_in[4];
  const float* pre_pos = (const float*)d_in[5];
  const float* Wc      = (const float*)d_in[6];
  const float* bc      = (const float*)d_in[7];
  const float* bert_pos= (const float*)d_in[8];
  const float* bert_tok= (const float*)d_in[9];
  const float* eln_g   = (const float*)d_in[10];
  const float* eln_b   = (const float*)d_in[11];
  const float* Wqkv    = (const float*)d_in[12];
  const float* bqkv    = (const float*)d_in[13];
  const float* Wo      = (const float*)d_in[14];
  const float* bo      = (const float*)d_in[15];
  const float* ln1g    = (const float*)d_in[16];
  const float* ln1b    = (const float*)d_in[17];
  const float* Cq      = (const float*)d_in[18];
  const float* cbq     = (const float*)d_in[19];
  const float* Ckv     = (const float*)d_in[20];
  const float* cbkv    = (const float*)d_in[21];
  const float* Co      = (const float*)d_in[22];
  const float* cbo     = (const float*)d_in[23];
  const float* ln2g    = (const float*)d_in[24];
  const float* ln2b    = (const float*)d_in[25];
  const float* W1      = (const float*)d_in[26];
  const float* b1      = (const float*)d_in[27];
  const float* W2      = (const float*)d_in[28];
  const float* b2      = (const float*)d_in[29];
  const float* ln3g    = (const float*)d_in[30];
  const float* ln3b    = (const float*)d_in[31];
  const float* Wnar    = (const float*)d_in[32];
  const float* bnar    = (const float*)d_in[33];
  const float* W_ih    = (const float*)d_in[34];
  const float* W_hh    = (const float*)d_in[35];
  const float* b_ih    = (const float*)d_in[36];
  const float* b_hh    = (const float*)d_in[37];
  const float* Wout    = (const float*)d_in[38];
  const float* bout    = (const float*)d_in[39];

  char* ws = (char*)d_ws;
  auto U = [&](size_t off) -> u16* { return (u16*)(ws + off); };
  auto F = [&](size_t off) -> float* { return (float*)(ws + off); };

  float* accum = F(o_acc);
  unsigned* flags = (unsigned*)(ws + o_flags);
  zero_kernel<<<dim3(1), dim3(64), 0, stream>>>(accum);

  auto gemm = [&](const u16* A, const u16* BT, const float* bias, float* Cf, u16* Cb,
                  int M, int N, int K, int lda, int ldb, int ldc, int relu, int accf) {
    dim3 grid((M / 128) * (N / 128));
    if (Cb && relu)
      gemm_kernel<true, false, true, false><<<grid, 256, 0, stream>>>(A, BT, bias, nullptr, Cb, M, N, K, lda, ldb, ldc);
    else if (Cb)
      gemm_kernel<false, false, true, false><<<grid, 256, 0, stream>>>(A, BT, bias, nullptr, Cb, M, N, K, lda, ldb, ldc);
    else if (accf)
      gemm_kernel<false, true, false, true><<<grid, 256, 0, stream>>>(A, BT, bias, Cf, nullptr, M, N, K, lda, ldb, ldc);
    else
      gemm_kernel<false, true, false, false><<<grid, 256, 0, stream>>>(A, BT, bias, Cf, nullptr, M, N, K, lda, ldb, ldc);
  };

  // ---- persistent weight conversions ----
  cvt_perm_kernel<<<dim3(4096), 256, 0, stream>>>(W_ih, U(o_Wihp), 640);
  cvt_perm_kernel<<<dim3(4096), 256, 0, stream>>>(W_hh, U(o_Whhp), 1024);
  bias_perm_kernel<<<dim3(16), 256, 0, stream>>>(b_ih, b_hh, F(o_bsum));
  cvt_transpose_kernel<<<dim3(8, 48), 256, 0, stream>>>(Wout, U(o_WoutT), 1536, 256);
  cvt_kernel<<<dim3(4096), 256, 0, stream>>>(enc, U(a_enc), 32 * 256 * 1024);

  // ---- embedding + char->pseudoword ----
  cvt_transpose_kernel<<<dim3(32, 4), 256, 0, stream>>>(Wc, U(a_wl), 128, 1024);
  embed_kernel<<<dim3(32000), dim3(128), 0, stream>>>(tgt, char_emb, pre_pos, U(s_emb));
  gemm(U(s_emb), U(a_wl), bc, nullptr, U(s_hbf), 32000, 1024, 128, 128, 128, 1024, 1, 0);
  pool_bert_ln_kernel<<<dim3(6400), 256, 0, stream>>>(
      U(s_hbf), tmask, bert_pos, bert_tok, eln_g, eln_b, F(a_x), U(a_xbf), F(o_smask));

  // ---- transformer layers ----
  for (int l = 0; l < 6; ++l) {
    cvt_transpose_kernel<<<dim3(96, 32), 256, 0, stream>>>(Wqkv + (size_t)l * 1024 * 3072, U(wl_qkv), 1024, 3072);
    cvt_transpose_kernel<<<dim3(32, 32), 256, 0, stream>>>(Wo + (size_t)l * 1024 * 1024, U(wl_wo), 1024, 1024);
    cvt_transpose_kernel<<<dim3(32, 32), 256, 0, stream>>>(Cq + (size_t)l * 1024 * 1024, U(wl_cq), 1024, 1024);
    cvt_transpose_kernel<<<dim3(64, 32), 256, 0, stream>>>(Ckv + (size_t)l * 1024 * 2048, U(wl_ckv), 1024, 2048);
    cvt_transpose_kernel<<<dim3(32, 32), 256, 0, stream>>>(Co + (size_t)l * 1024 * 1024, U(wl_co), 1024, 1024);
    cvt_transpose_kernel<<<dim3(64, 32), 256, 0, stream>>>(W1 + (size_t)l * 1024 * 2048, U(wl_w1), 1024, 2048);
    cvt_transpose_kernel<<<dim3(32, 64), 256, 0, stream>>>(W2 + (size_t)l * 2048 * 1024, U(wl_w2), 2048, 1024);

    // self-attention
    gemm(U(a_xbf), U(wl_qkv), bqkv + l * 3072, nullptr, U(s_qkv), 6400, 3072, 1024, 1024, 1024, 3072, 0, 0);
    vtrans_kernel<<<dim3(512), 256, 0, stream>>>(U(s_qkv), 3072, 2048, 200, U(s_vT));
    scores_kernel<<<dim3(1664), 256, 0, stream>>>(
        U(s_qkv), 3072, U(s_qkv), 3072, 1024, 200, F(o_smask), U(s_P), 1);
    pv_kernel<<<dim3(1664), 256, 0, stream>>>(U(s_P), U(s_vT), U(s_S2));
    gemm(U(s_S2), U(wl_wo), bo + l * 1024, F(s_o32), nullptr, 6400, 1024, 1024, 1024, 1024, 1024, 0, 0);
    resid_ln_kernel<<<dim3(6400), 256, 0, stream>>>(F(a_x), F(s_o32), ln1g + l * 1024, ln1b + l * 1024, U(a_xbf));

    // cross-attention
    gemm(U(a_xbf), U(wl_cq), cbq + l * 1024, nullptr, U(s_qkv), 6400, 1024, 1024, 1024, 1024, 1024, 0, 0);
    gemm(U(a_enc), U(wl_ckv), cbkv + l * 2048, nullptr, U(s_kvc), 8192, 2048, 1024, 1024, 1024, 2048, 0, 0);
    vtrans_kernel<<<dim3(512), 256, 0, stream>>>(U(s_kvc), 2048, 1024, 256, U(s_vT));
    scores_kernel<<<dim3(1664), 256, 0, stream>>>(
        U(s_qkv), 1024, U(s_kvc), 2048, 0, 256, encmask, U(s_P), 0);
    pv_kernel<<<dim3(1664), 256, 0, stream>>>(U(s_P), U(s_vT), U(s_S2));
    gemm(U(s_S2), U(wl_co), cbo + l * 1024, F(s_o32), nullptr, 6400, 1024, 1024, 1024, 1024, 1024, 0, 0);
    resid_ln_kernel<<<dim3(6400), 256, 0, stream>>>(F(a_x), F(s_o32), ln2g + l * 1024, ln2b + l * 1024, U(a_xbf));

    // FFN
    gemm(U(a_xbf), U(wl_w1), b1 + l * 2048, nullptr, U(s_S2), 6400, 2048, 1024, 1024, 1024, 2048, 1, 0);
    gemm(U(s_S2), U(wl_w2), b2 + l * 1024, F(s_o32), nullptr, 6400, 1024, 2048, 2048, 2048, 1024, 0, 0);
    resid_ln_kernel<<<dim3(6400), 256, 0, stream>>>(F(a_x), F(s_o32), ln3g + l * 1024, ln3b + l * 1024, U(a_xbf));
  }

  // ---- nar proj -> char states ----
  cvt_transpose_kernel<<<dim3(80, 32), 256, 0, stream>>>(Wnar, U(a_wl), 1024, 2560);
  gemm(U(a_xbf), U(a_wl), bnar, nullptr, U(o_cs), 6400, 2560, 1024, 1024, 1024, 2560, 0, 0);

  // ---- LSTM input (time-major) ----
  lstmin_kernel<<<dim3(32000), dim3(640), 0, stream>>>(tgt, char_emb, U(o_cs), U(b_lin));

  // ---- chunked xproj GEMM + LSTM ----
  for (int c = 0; c < 2; ++c) {
    gemm(U(b_lin) + (size_t)c * 16000 * 640, U(o_Wihp), F(o_bsum), nullptr, U(b_xpj),
         16000, 4096, 640, 640, 640, 4096, 0, 0);
    flags_reset_kernel<<<dim3(1), 256, 0, stream>>>(flags);
    const u16* xprojp = U(b_xpj);
    const u16* Wpp = U(o_Whhp);
    u16* hbufp = U(o_hbuf);
    float* cbufp = F(o_cbuf);
    u16* loutp = U(o_lout);
    unsigned* flagsp = flags;
    int t0 = c * 500, ns = 500;
    void* kargs[] = { &xprojp, &Wpp, &hbufp, &cbufp, &loutp, &flagsp, &t0, &ns };
    hipLaunchCooperativeKernel(lstm_kernel, dim3(64), dim3(256), kargs, 0u, stream);
  }

  // ---- output projection (split concat) + NLL ----
  gemm(U(o_lout), U(o_WoutT), bout, F(b_xpj), nullptr, 32000, 256, 1024, 1024, 1536, 256, 0, 0);
  gemm(U(o_cs), U(o_WoutT) + 1024, nullptr, F(b_xpj), nullptr, 32000, 256, 512, 512, 1536, 256, 0, 1);
  nll_kernel<<<dim3(2000), 256, 0, stream>>>(F(b_xpj), tgt, tmask, accum);
  finalize_kernel<<<dim3(1), dim3(64), 0, stream>>>(accum, (float*)d_out);
}

// Round 4
// 13313.550 us; speedup vs baseline: 2.8109x; 1.1027x over previous
//
#include <hip/hip_runtime.h>
#include <cstdint>
#include <cstddef>

#define DEV __device__ __forceinline__

typedef unsigned short u16;
typedef __attribute__((ext_vector_type(8))) short short8;
typedef __attribute__((ext_vector_type(4))) float floatx4;

DEV float bf2f(u16 h) { union { unsigned u; float f; } c; c.u = ((unsigned)h) << 16; return c.f; }
DEV u16 f2bf(float f) {
  union { float f; unsigned u; } c; c.f = f;
  unsigned r = 0x7fffu + ((c.u >> 16) & 1u);
  return (u16)((c.u + r) >> 16);
}
DEV short8 ld8(const u16* p) { return *(const short8*)p; }
DEV floatx4 mfma16(short8 a, short8 b, floatx4 c) {
  return __builtin_amdgcn_mfma_f32_16x16x32_bf16(a, b, c, 0, 0, 0);
}
DEV void async16(const u16* g, u16* l) {
  __builtin_amdgcn_global_load_lds((__attribute__((address_space(1))) void*)(uintptr_t)(const void*)g,
                                   (__attribute__((address_space(3))) void*)(uintptr_t)(void*)l, 16, 0, 0);
}
DEV float sigm(float x) { return 1.f / (1.f + __expf(-x)); }

DEV float blk_sum256(float v) {
  __shared__ float sh[4];
  #pragma unroll
  for (int d = 32; d >= 1; d >>= 1) v += __shfl_xor(v, d, 64);
  if ((threadIdx.x & 63) == 0) sh[threadIdx.x >> 6] = v;
  __syncthreads();
  v = sh[0] + sh[1] + sh[2] + sh[3];
  __syncthreads();
  return v;
}

// ---------------- generic bf16 MFMA GEMM: C = A[M,K] * BT[N,K]^T (+bias) ----------------
template<bool RELU, bool WF32, bool WBF16, bool ACC>
__global__ __launch_bounds__(256, 2) void gemm_kernel(
    const u16* __restrict__ A, const u16* __restrict__ BT,
    const float* __restrict__ bias, float* __restrict__ Cf, u16* __restrict__ Cb,
    int M, int N, int K, int lda, int ldb, int ldc)
{
  __shared__ u16 As[4096];
  __shared__ u16 Bs[4096];
  const int tid = threadIdx.x;
  const int lane = tid & 63;
  const int w = tid >> 6;
  const int nTiles = N >> 7;
  const int bm = blockIdx.x / nTiles;
  const int bn = blockIdx.x - bm * nTiles;
  const int m0 = bm << 7, n0 = bn << 7;
  const int q = lane >> 4, lm = lane & 15;
  const int wm = (w & 1) << 6, wn = (w >> 1) << 6;

  const int s1 = tid, s2 = tid + 256;
  const int r1 = s1 >> 2, c1 = (s1 & 3) ^ ((r1 >> 2) & 3);
  const int r2 = s2 >> 2, c2 = (s2 & 3) ^ ((r2 >> 2) & 3);
  const u16* ga1 = A + (size_t)(m0 + r1) * lda + c1 * 8;
  const u16* ga2 = A + (size_t)(m0 + r2) * lda + c2 * 8;
  const u16* gb1 = BT + (size_t)(n0 + r1) * ldb + c1 * 8;
  const u16* gb2 = BT + (size_t)(n0 + r2) * ldb + c2 * 8;

  floatx4 acc[4][4] = {};

  for (int kt = 0; kt < K; kt += 32) {
    async16(ga1 + kt, &As[s1 * 8]);
    async16(ga2 + kt, &As[s2 * 8]);
    async16(gb1 + kt, &Bs[s1 * 8]);
    async16(gb2 + kt, &Bs[s2 * 8]);
    __syncthreads();
    short8 af[4], bfr[4];
    #pragma unroll
    for (int i = 0; i < 4; ++i) {
      int r = wm + i * 16 + lm;
      af[i] = ld8(&As[(r * 4 + (q ^ ((r >> 2) & 3))) * 8]);
      r = wn + i * 16 + lm;
      bfr[i] = ld8(&Bs[(r * 4 + (q ^ ((r >> 2) & 3))) * 8]);
    }
    #pragma unroll
    for (int mi = 0; mi < 4; ++mi)
      #pragma unroll
      for (int ni = 0; ni < 4; ++ni)
        acc[mi][ni] = mfma16(af[mi], bfr[ni], acc[mi][ni]);
    __syncthreads();
  }
  #pragma unroll
  for (int ni = 0; ni < 4; ++ni) {
    int col = n0 + wn + ni * 16 + lm;
    float bv = ACC ? 0.f : bias[col];
    #pragma unroll
    for (int mi = 0; mi < 4; ++mi) {
      int rowb = m0 + wm + mi * 16 + q * 4;
      #pragma unroll
      for (int r = 0; r < 4; ++r) {
        float v = acc[mi][ni][r] + bv;
        if (RELU) v = fmaxf(v, 0.f);
        size_t idx = (size_t)(rowb + r) * ldc + col;
        if (WF32) { if (ACC) Cf[idx] += v; else Cf[idx] = v; }
        if (WBF16) Cb[idx] = f2bf(v);
      }
    }
  }
}

// ---------------- weight conversion kernels ----------------
__global__ __launch_bounds__(256) void cvt_transpose_kernel(
    const float* __restrict__ src, u16* __restrict__ dst, int K, int N)
{
  __shared__ float tile[32][33];
  int n0 = blockIdx.x * 32, k0 = blockIdx.y * 32;
  int tx = threadIdx.x & 31, ty = threadIdx.x >> 5;
  #pragma unroll
  for (int i = 0; i < 32; i += 8)
    tile[ty + i][tx] = src[(size_t)(k0 + ty + i) * N + n0 + tx];
  __syncthreads();
  #pragma unroll
  for (int i = 0; i < 32; i += 8)
    dst[(size_t)(n0 + ty + i) * K + k0 + tx] = f2bf(tile[tx][ty + i]);
}

__global__ void cvt_kernel(const float* __restrict__ s, u16* __restrict__ d, int n) {
  int i = blockIdx.x * 256 + threadIdx.x;
  int stride = gridDim.x * 256;
  for (; i < n; i += stride) d[i] = f2bf(s[i]);
}

// permute gate rows: dst row q <- src row (q&3)*1024 + (q>>2)
__global__ void cvt_perm_kernel(const float* __restrict__ src, u16* __restrict__ dst, int cols) {
  int qrow = blockIdx.x;
  int orig = (qrow & 3) * 1024 + (qrow >> 2);
  const float* sp = src + (size_t)orig * cols;
  u16* dp = dst + (size_t)qrow * cols;
  for (int c = threadIdx.x; c < cols; c += 256) dp[c] = f2bf(sp[c]);
}

__global__ void bias_perm_kernel(const float* __restrict__ bih, const float* __restrict__ bhh,
                                 float* __restrict__ bsum) {
  int q = blockIdx.x * 256 + threadIdx.x;
  int orig = (q & 3) * 1024 + (q >> 2);
  bsum[q] = bih[orig] + bhh[orig];
}

// ---------------- embedding / pooling / LN ----------------
__global__ void embed_kernel(const int* __restrict__ tgt, const float* __restrict__ ce,
                             const float* __restrict__ pp, u16* __restrict__ out) {
  int row = blockIdx.x;
  int b = row / 1000, s = row - b * 1000;
  int id = (s < 5) ? 1 : tgt[b * 1000 + s - 5];
  int e = threadIdx.x;
  out[(size_t)row * 128 + e] = f2bf(ce[id * 128 + e] + pp[s * 128 + e]);
}

__global__ __launch_bounds__(256) void pool_bert_ln_kernel(
    const u16* __restrict__ hb, const float* __restrict__ tmask,
    const float* __restrict__ pos, const float* __restrict__ tok,
    const float* __restrict__ g, const float* __restrict__ bt,
    float* __restrict__ x, u16* __restrict__ xb, float* __restrict__ smaskOut)
{
  int row = blockIdx.x, b = row / 200, t = row - b * 200;
  int tid = threadIdx.x;
  float m[4] = {0.f, 0.f, 0.f, 0.f};
  float sm = 0.f;
  for (int wi = 0; wi < 5; ++wi) {
    int s = t * 5 + wi;
    float im = (s < 5) ? 1.f : tmask[b * 1000 + s - 5];
    sm = fmaxf(sm, im);
    const u16* hr = hb + (size_t)(b * 1000 + s) * 1024;
    #pragma unroll
    for (int i = 0; i < 4; ++i) {
      int d = tid + i * 256;
      m[i] = fmaxf(m[i], bf2f(hr[d]) * im);
    }
  }
  float y[4]; float ssum = 0.f;
  #pragma unroll
  for (int i = 0; i < 4; ++i) {
    int d = tid + i * 256;
    y[i] = m[i] + pos[t * 1024 + d] + tok[d];
    ssum += y[i];
  }
  float mean = blk_sum256(ssum) * (1.f / 1024.f);
  float vs = 0.f;
  #pragma unroll
  for (int i = 0; i < 4; ++i) { float dd = y[i] - mean; vs += dd * dd; }
  float var = blk_sum256(vs) * (1.f / 1024.f);
  float rs = rsqrtf(var + 1e-12f);
  #pragma unroll
  for (int i = 0; i < 4; ++i) {
    int d = tid + i * 256;
    float o = (y[i] - mean) * rs * g[d] + bt[d];
    x[(size_t)row * 1024 + d] = o;
    xb[(size_t)row * 1024 + d] = f2bf(o);
  }
  if (tid == 0) smaskOut[row] = sm;
}

__global__ __launch_bounds__(256) void resid_ln_kernel(
    float* __restrict__ x, const float* __restrict__ o,
    const float* __restrict__ g, const float* __restrict__ bt,
    u16* __restrict__ xb)
{
  size_t row = blockIdx.x;
  int tid = threadIdx.x;
  float y[4]; float s = 0.f;
  #pragma unroll
  for (int i = 0; i < 4; ++i) {
    int d = tid + i * 256;
    y[i] = x[row * 1024 + d] + o[row * 1024 + d];
    s += y[i];
  }
  float mean = blk_sum256(s) * (1.f / 1024.f);
  float vs = 0.f;
  #pragma unroll
  for (int i = 0; i < 4; ++i) { float dd = y[i] - mean; vs += dd * dd; }
  float var = blk_sum256(vs) * (1.f / 1024.f);
  float rs = rsqrtf(var + 1e-12f);
  #pragma unroll
  for (int i = 0; i < 4; ++i) {
    int d = tid + i * 256;
    float out = (y[i] - mean) * rs * g[d] + bt[d];
    x[row * 1024 + d] = out;
    xb[row * 1024 + d] = f2bf(out);
  }
}

// ---------------- attention: fused QK^T + softmax -> P (bf16) ----------------
__global__ __launch_bounds__(256) void scores_kernel(
    const u16* __restrict__ Q, int qstride,
    const u16* __restrict__ Kp, int kstride, int kcoff, int krows,
    const float* __restrict__ mask, u16* __restrict__ P, int selfmode)
{
  int wid = blockIdx.x * 4 + (threadIdx.x >> 6);
  int lane = threadIdx.x & 63;
  int qt = wid % 13, h = (wid / 13) & 15, b = wid / 208;
  int lm = lane & 15, quad = lane >> 4;
  int t0 = qt * 16;
  int trow = t0 + lm; if (trow > 199) trow = 199;
  const u16* qp = Q + (size_t)(b * 200 + trow) * qstride + h * 64;
  short8 a0 = ld8(qp + quad * 8);
  short8 a1 = ld8(qp + 32 + quad * 8);
  floatx4 S[16];
  const int nmf = selfmode ? 13 : 16;
  for (int ut = 0; ut < nmf; ++ut) {
    int ur = ut * 16 + lm; if (ur >= krows) ur = krows - 1;
    const u16* kp = Kp + (size_t)(b * krows + ur) * kstride + kcoff + h * 64;
    floatx4 z = {0.f, 0.f, 0.f, 0.f};
    z = mfma16(a0, ld8(kp + quad * 8), z);
    z = mfma16(a1, ld8(kp + 32 + quad * 8), z);
    S[ut] = z;
  }
  for (int ut = nmf; ut < 16; ++ut) S[ut] = (floatx4){0.f, 0.f, 0.f, 0.f};
  const float scale = 0.125f;
  u16* prow_base = P + (size_t)((b * 16 + h) * 200) * 256;
  for (int r = 0; r < 4; ++r) {
    int t = t0 + quad * 4 + r;
    float mx = -3e38f;
    float vv[16];
    #pragma unroll
    for (int ut = 0; ut < 16; ++ut) {
      int u = ut * 16 + lm;
      float bias;
      if (selfmode) {
        bias = ((u <= t && u < 200) ? 0.f : -1e9f);
        if (u < 200) bias += (1.f - mask[b * 200 + u]) * -1e9f;
      } else {
        bias = (1.f - mask[b * 256 + u]) * -1e9f;
      }
      float v = S[ut][r] * scale + bias;
      vv[ut] = v;
      mx = fmaxf(mx, v);
    }
    #pragma unroll
    for (int d = 1; d < 16; d <<= 1) mx = fmaxf(mx, __shfl_xor(mx, d, 64));
    float sum = 0.f;
    #pragma unroll
    for (int ut = 0; ut < 16; ++ut) { float e = __expf(vv[ut] - mx); vv[ut] = e; sum += e; }
    #pragma unroll
    for (int d = 1; d < 16; d <<= 1) sum += __shfl_xor(sum, d, 64);
    float inv = 1.f / sum;
    if (t < 200) {
      u16* pr = prow_base + (size_t)t * 256;
      #pragma unroll
      for (int ut = 0; ut < 16; ++ut) pr[ut * 16 + lm] = f2bf(vv[ut] * inv);
    }
  }
}

// transpose V slice -> vT[b,h,64,256]
__global__ __launch_bounds__(256) void vtrans_kernel(
    const u16* __restrict__ src, int stride, int coff, int krows, u16* __restrict__ vT)
{
  int b = blockIdx.x >> 4, h = blockIdx.x & 15;
  __shared__ u16 tile[64][257];
  for (int idx = threadIdx.x; idx < 256 * 64; idx += 256) {
    int u = idx >> 6, d = idx & 63;
    u16 v = 0;
    if (u < krows) v = src[(size_t)(b * krows + u) * stride + coff + h * 64 + d];
    tile[d][u] = v;
  }
  __syncthreads();
  u16* dst = vT + (size_t)((b * 16 + h) * 64) * 256;
  for (int idx = threadIdx.x; idx < 64 * 256; idx += 256) {
    int d = idx >> 8, u = idx & 255;
    dst[(size_t)d * 256 + u] = tile[d][u];
  }
}

__global__ __launch_bounds__(256) void pv_kernel(
    const u16* __restrict__ P, const u16* __restrict__ vT, u16* __restrict__ O)
{
  int wid = blockIdx.x * 4 + (threadIdx.x >> 6);
  int lane = threadIdx.x & 63;
  int qt = wid % 13, h = (wid / 13) & 15, b = wid / 208;
  int lm = lane & 15, quad = lane >> 4;
  int t0 = qt * 16;
  int trow = t0 + lm; if (trow > 199) trow = 199;
  const u16* prow = P + ((size_t)((b * 16 + h) * 200) + trow) * 256;
  const u16* vbase = vT + (size_t)((b * 16 + h) * 64) * 256;
  floatx4 acc[4] = {};
  #pragma unroll
  for (int kb = 0; kb < 8; ++kb) {
    short8 a = ld8(prow + kb * 32 + quad * 8);
    #pragma unroll
    for (int dn = 0; dn < 4; ++dn) {
      short8 bb = ld8(vbase + (size_t)(dn * 16 + lm) * 256 + kb * 32 + quad * 8);
      acc[dn] = mfma16(a, bb, acc[dn]);
    }
  }
  #pragma unroll
  for (int dn = 0; dn < 4; ++dn)
    #pragma unroll
    for (int r = 0; r < 4; ++r) {
      int t = t0 + quad * 4 + r;
      if (t < 200)
        O[(size_t)(b * 200 + t) * 1024 + h * 64 + dn * 16 + lm] = f2bf(acc[dn][r]);
    }
}

// ---------------- LSTM prep (time-major lin rows = s*32+b; also time-major cst) ----------------
__global__ void lstmin_kernel(const int* __restrict__ tgt, const float* __restrict__ ce,
                              const u16* __restrict__ cs, u16* __restrict__ out,
                              u16* __restrict__ cst) {
  int row = blockIdx.x;
  int b = row / 1000, s = row - b * 1000;
  int c = threadIdx.x;
  u16 v;
  if (c < 128) {
    int id = (s == 0) ? 1 : tgt[b * 1000 + s - 1];
    v = f2bf(ce[id * 128 + c]);
  } else {
    v = cs[(size_t)row * 512 + (c - 128)];   // cs viewed as [32000,512]
    cst[(size_t)(s * 32 + b) * 512 + (c - 128)] = v;
  }
  out[(size_t)(s * 32 + b) * 640 + c] = v;
}

// ---------------- LSTM: fence-free step protocol ----------------
// h history ring == lout (time-major [t][32][1024] bf16). Step t writes h(t) to fresh
// addresses via agent-scope atomic dwords (visible at L3); readers touch each line only
// after the writer's flag, and each address only once per dispatch => no stale L2, no
// buffer_inv/wbl2 per step. Flags: one cache line per block, relaxed agent loads/stores.
__global__ __launch_bounds__(256, 1) void lstm_kernel(
    const u16* __restrict__ xproj, const u16* __restrict__ Wp,
    u16* __restrict__ lout, const u16* __restrict__ zbuf,
    float* __restrict__ cbuf, unsigned* __restrict__ flags, int t0, int nsteps)
{
  __shared__ u16 smem[32768];            // 64 KB h staging, aliased as f32 gate buffer
  float* g_all = (float*)smem;           // [32][66]

  const int tid = threadIdx.x;
  const int lane = tid & 63;
  const int w = tid >> 6;
  const int bk = blockIdx.x;             // 64 blocks x 64 gate cols (16 h units)
  const int lm = lane & 15, quad = lane >> 4;
  const int Q0 = bk * 64;

  short8 wfrag[32];
  #pragma unroll
  for (int kk = 0; kk < 32; ++kk)
    wfrag[kk] = ld8(Wp + (size_t)(Q0 + w * 16 + lm) * 1024 + kk * 32 + quad * 8);

  const int b_ = tid >> 3;               // batch 0..31
  const int u0 = (tid & 7) * 2;          // 2 hidden units per thread
  float c0 = 0.f, c1 = 0.f;
  if (t0 != 0) {
    c0 = cbuf[b_ * 1024 + bk * 16 + u0];
    c1 = cbuf[b_ * 1024 + bk * 16 + u0 + 1];
  }

  for (int ltt = 0; ltt < nsteps; ++ltt) {
    const int t = t0 + ltt;

    // prefetch xproj fragment (read-only, fresh at dispatch start)
    short8 xp = ld8(xproj + (size_t)(ltt * 32 + b_) * 4096 + Q0 + u0 * 4);

    // wait for all blocks to have completed step ltt-1 (none needed for first step)
    if (ltt > 0) {
      if (w == 0) {
        unsigned want = (unsigned)ltt;
        int spin = 0;
        for (;;) {
          unsigned v = __hip_atomic_load(&flags[lane * 16], __ATOMIC_RELAXED, __HIP_MEMORY_SCOPE_AGENT);
          if (__all((int)(v >= want))) break;
          if (((++spin) & 1023) == 0) __builtin_amdgcn_fence(__ATOMIC_ACQUIRE, "agent");
          __builtin_amdgcn_s_sleep(1);
        }
      }
      __syncthreads();
    }

    // stage h(t-1) [32][1024] into LDS (xor-swizzled)
    const u16* hsrc = (t == 0) ? zbuf : (lout + (size_t)(t - 1) * 32768);
    #pragma unroll
    for (int it = 0; it < 16; ++it) {
      int i = it * 2048 + tid * 8;
      int b = i >> 10, c = i & 1023;
      short8 v = ld8(hsrc + (size_t)b * 1024 + c);
      *(short8*)&smem[b * 1024 + (c ^ ((b & 7) * 8))] = v;
    }
    __syncthreads();

    // gates = h @ Wp^T (block's 64 cols; each wave full K)
    floatx4 acc0 = {0.f, 0.f, 0.f, 0.f}, acc1 = {0.f, 0.f, 0.f, 0.f};
    #pragma unroll
    for (int kk = 0; kk < 32; ++kk) {
      int cix = kk * 32 + quad * 8;
      short8 a0 = ld8(&smem[lm * 1024 + (cix ^ ((lm & 7) * 8))]);
      short8 a1 = ld8(&smem[(16 + lm) * 1024 + (cix ^ ((lm & 7) * 8))]);
      acc0 = mfma16(a0, wfrag[kk], acc0);
      acc1 = mfma16(a1, wfrag[kk], acc1);
    }
    __syncthreads();                      // staging reads done before aliased g_all dump
    #pragma unroll
    for (int r = 0; r < 4; ++r) {
      g_all[(quad * 4 + r) * 66 + w * 16 + lm] = acc0[r];
      g_all[(16 + quad * 4 + r) * 66 + w * 16 + lm] = acc1[r];
    }
    __syncthreads();

    // nonlinearity: 2 hidden units per thread
    const u16* xpp = (const u16*)&xp;
    const float* gb = g_all + b_ * 66 + u0 * 4;
    float gi = gb[0] + bf2f(xpp[0]);
    float gf = gb[1] + bf2f(xpp[1]);
    float gg = gb[2] + bf2f(xpp[2]);
    float go = gb[3] + bf2f(xpp[3]);
    c0 = sigm(gf) * c0 + sigm(gi) * tanhf(gg);
    float h0v = sigm(go) * tanhf(c0);
    gi = gb[4] + bf2f(xpp[4]);
    gf = gb[5] + bf2f(xpp[5]);
    gg = gb[6] + bf2f(xpp[6]);
    go = gb[7] + bf2f(xpp[7]);
    c1 = sigm(gf) * c1 + sigm(gi) * tanhf(gg);
    float h1v = sigm(go) * tanhf(c1);

    // publish h(t): one agent-scope dword per thread (device-coherent)
    unsigned hval = ((unsigned)f2bf(h1v) << 16) | (unsigned)f2bf(h0v);
    unsigned* hdst = (unsigned*)(lout + (size_t)t * 32768 + b_ * 1024 + bk * 16 + u0);
    __hip_atomic_store(hdst, hval, __ATOMIC_RELAXED, __HIP_MEMORY_SCOPE_AGENT);

    __syncthreads();                      // all waves' stores vmcnt-retired
    if (w == 0) {
      __builtin_amdgcn_fence(__ATOMIC_RELEASE, "agent");
      if (lane == 0)
        __hip_atomic_store(&flags[bk * 16], (unsigned)(ltt + 1), __ATOMIC_RELAXED, __HIP_MEMORY_SCOPE_AGENT);
    }
  }
  cbuf[b_ * 1024 + bk * 16 + u0] = c0;
  cbuf[b_ * 1024 + bk * 16 + u0 + 1] = c1;
}

// ---------------- NLL (logits rows time-major: row = t*32+b) ----------------
__global__ __launch_bounds__(256) void nll_kernel(
    const float* __restrict__ logits, const int* __restrict__ tgt,
    const float* __restrict__ tmask, float* __restrict__ acc)
{
  int wid = blockIdx.x * 4 + (threadIdx.x >> 6);
  int lane = threadIdx.x & 63;
  float ls = 0.f, ms = 0.f;
  for (int rr = 0; rr < 4; ++rr) {
    int row = wid * 4 + rr;
    int bix = (row & 31) * 1000 + (row >> 5);
    const float* lp = logits + (size_t)row * 256;
    float v[4]; float mx = -3e38f;
    #pragma unroll
    for (int i = 0; i < 4; ++i) { v[i] = lp[lane + i * 64]; mx = fmaxf(mx, v[i]); }
    #pragma unroll
    for (int d = 1; d < 64; d <<= 1) mx = fmaxf(mx, __shfl_xor(mx, d, 64));
    float s = 0.f;
    #pragma unroll
    for (int i = 0; i < 4; ++i) s += __expf(v[i] - mx);
    #pragma unroll
    for (int d = 1; d < 64; d <<= 1) s += __shfl_xor(s, d, 64);
    float lse = mx + __logf(s);
    int tg = tgt[bix];
    float tv = 0.f;
    #pragma unroll
    for (int i = 0; i < 4; ++i) if (lane + i * 64 == tg) tv = v[i];
    #pragma unroll
    for (int d = 1; d < 64; d <<= 1) tv += __shfl_xor(tv, d, 64);
    float mk = tmask[bix];
    ls += (lse - tv) * mk;
    ms += mk;
  }
  if (lane == 0) { atomicAdd(&acc[0], ls); atomicAdd(&acc[1], ms); }
}

__global__ void zero_kernel(float* acc) {
  if (threadIdx.x == 0) { acc[0] = 0.f; acc[1] = 0.f; }
}
__global__ void flags_reset_kernel(unsigned* flags) {
  int i = threadIdx.x;
  #pragma unroll
  for (int k = 0; k < 4; ++k) flags[i + k * 256] = 0u;
}
__global__ void zfill_kernel(unsigned* p) {
  p[blockIdx.x * 256 + threadIdx.x] = 0u;
}
__global__ void finalize_kernel(const float* acc, float* out) {
  if (threadIdx.x == 0) out[0] = acc[0] / acc[1];
}
__global__ void diag_kernel(float* out, float v) {
  if (threadIdx.x == 0) out[0] = v;
}

// ---------------- workspace layout (bytes) ----------------
constexpr size_t AL(size_t x) { return (x + 255) & ~(size_t)255; }
constexpr size_t o_Wihp  = 0;
constexpr size_t o_Whhp  = AL(o_Wihp + 4096ull * 640 * 2);
constexpr size_t o_WoutT = AL(o_Whhp + 4096ull * 1024 * 2);
constexpr size_t o_bsum  = AL(o_WoutT + 256ull * 1536 * 2);
constexpr size_t o_zbuf  = AL(o_bsum + 4096ull * 4);          // 64 KB zero h(-1)
constexpr size_t o_cbuf  = AL(o_zbuf + 65536);
constexpr size_t o_acc   = AL(o_cbuf + 32ull * 1024 * 4);
constexpr size_t o_flags = AL(o_acc + 256);
constexpr size_t o_smask = AL(o_flags + 4096);
constexpr size_t o_cs    = AL(o_smask + 6400ull * 4);
constexpr size_t o_lout  = AL(o_cs + 6400ull * 2560 * 2);     // time-major [1000][32][1024]
constexpr size_t o_arena = AL(o_lout + 32000ull * 1024 * 2);
// phase A arena
constexpr size_t a_wl    = o_arena;
constexpr size_t wl_qkv  = a_wl;
constexpr size_t wl_wo   = wl_qkv + 3072ull * 1024 * 2;
constexpr size_t wl_cq   = wl_wo + 1024ull * 1024 * 2;
constexpr size_t wl_ckv  = wl_cq + 1024ull * 1024 * 2;
constexpr size_t wl_co   = wl_ckv + 2048ull * 1024 * 2;
constexpr size_t wl_w1   = wl_co + 1024ull * 1024 * 2;
constexpr size_t wl_w2   = wl_w1 + 2048ull * 1024 * 2;
constexpr size_t a_enc   = AL(wl_w2 + 2048ull * 1024 * 2);
constexpr size_t a_x     = AL(a_enc + 8192ull * 1024 * 2);
constexpr size_t a_xbf   = AL(a_x + 6400ull * 1024 * 4);
constexpr size_t a_scr   = AL(a_xbf + 6400ull * 1024 * 2);
constexpr size_t s_qkv   = a_scr;
constexpr size_t s_kvc   = s_qkv + 6400ull * 1024 * 2;
constexpr size_t s_P     = AL(a_scr + 46661632ull);
constexpr size_t s_vT    = AL(s_P + 32ull * 16 * 200 * 256 * 2);
constexpr size_t s_S2    = AL(s_vT + 32ull * 16 * 64 * 256 * 2);
constexpr size_t s_o32   = AL(s_S2 + 6400ull * 2048 * 2);
constexpr size_t a_endA  = AL(s_o32 + 6400ull * 1024 * 4);
constexpr size_t s_emb   = a_scr;
constexpr size_t s_hbf   = a_scr + 32000ull * 128 * 2;
// phase B arena
constexpr size_t b_lin   = o_arena;
constexpr size_t b_xpj   = b_lin + 32000ull * 640 * 2;        // xproj chunk; logits alias
constexpr size_t o_cst   = AL(b_xpj + 16000ull * 4096 * 2);   // time-major char states
constexpr size_t b_end   = AL(o_cst + 32000ull * 512 * 2);
constexpr size_t WS_NEED = (a_endA > b_end ? a_endA : b_end);

extern "C" void kernel_launch(void* const* d_in, const int* in_sizes, int n_in,
                              void* d_out, int out_size, void* d_ws, size_t ws_size,
                              hipStream_t stream)
{
  if (ws_size < WS_NEED) {
    diag_kernel<<<dim3(1), dim3(64), 0, stream>>>((float*)d_out, (float)(ws_size >> 20));
    return;
  }
  const float* enc     = (const float*)d_in[0];
  const float* encmask = (const float*)d_in[1];
  const int*   tgt     = (const int*)d_in[2];
  const float* tmask   = (const float*)d_in[3];
  const float* char_emb= (const float*)d_in[4];
  const float* pre_pos = (const float*)d_in[5];
  const float* Wc      = (const float*)d_in[6];
  const float* bc      = (const float*)d_in[7];
  const float* bert_pos= (const float*)d_in[8];
  const float* bert_tok= (const float*)d_in[9];
  const float* eln_g   = (const float*)d_in[10];
  const float* eln_b   = (const float*)d_in[11];
  const float* Wqkv    = (const float*)d_in[12];
  const float* bqkv    = (const float*)d_in[13];
  const float* Wo      = (const float*)d_in[14];
  const float* bo      = (const float*)d_in[15];
  const float* ln1g    = (const float*)d_in[16];
  const float* ln1b    = (const float*)d_in[17];
  const float* Cq      = (const float*)d_in[18];
  const float* cbq     = (const float*)d_in[19];
  const float* Ckv     = (const float*)d_in[20];
  const float* cbkv    = (const float*)d_in[21];
  const float* Co      = (const float*)d_in[22];
  const float* cbo     = (const float*)d_in[23];
  const float* ln2g    = (const float*)d_in[24];
  const float* ln2b    = (const float*)d_in[25];
  const float* W1      = (const float*)d_in[26];
  const float* b1      = (const float*)d_in[27];
  const float* W2      = (const float*)d_in[28];
  const float* b2      = (const float*)d_in[29];
  const float* ln3g    = (const float*)d_in[30];
  const float* ln3b    = (const float*)d_in[31];
  const float* Wnar    = (const float*)d_in[32];
  const float* bnar    = (const float*)d_in[33];
  const float* W_ih    = (const float*)d_in[34];
  const float* W_hh    = (const float*)d_in[35];
  const float* b_ih    = (const float*)d_in[36];
  const float* b_hh    = (const float*)d_in[37];
  const float* Wout    = (const float*)d_in[38];
  const float* bout    = (const float*)d_in[39];

  char* ws = (char*)d_ws;
  auto U = [&](size_t off) -> u16* { return (u16*)(ws + off); };
  auto F = [&](size_t off) -> float* { return (float*)(ws + off); };

  float* accum = F(o_acc);
  unsigned* flags = (unsigned*)(ws + o_flags);
  zero_kernel<<<dim3(1), dim3(64), 0, stream>>>(accum);
  zfill_kernel<<<dim3(64), 256, 0, stream>>>((unsigned*)(ws + o_zbuf));

  auto gemm = [&](const u16* A, const u16* BT, const float* bias, float* Cf, u16* Cb,
                  int M, int N, int K, int lda, int ldb, int ldc, int relu, int accf) {
    dim3 grid((M / 128) * (N / 128));
    if (Cb && relu)
      gemm_kernel<true, false, true, false><<<grid, 256, 0, stream>>>(A, BT, bias, nullptr, Cb, M, N, K, lda, ldb, ldc);
    else if (Cb)
      gemm_kernel<false, false, true, false><<<grid, 256, 0, stream>>>(A, BT, bias, nullptr, Cb, M, N, K, lda, ldb, ldc);
    else if (accf)
      gemm_kernel<false, true, false, true><<<grid, 256, 0, stream>>>(A, BT, bias, Cf, nullptr, M, N, K, lda, ldb, ldc);
    else
      gemm_kernel<false, true, false, false><<<grid, 256, 0, stream>>>(A, BT, bias, Cf, nullptr, M, N, K, lda, ldb, ldc);
  };

  // ---- persistent weight conversions ----
  cvt_perm_kernel<<<dim3(4096), 256, 0, stream>>>(W_ih, U(o_Wihp), 640);
  cvt_perm_kernel<<<dim3(4096), 256, 0, stream>>>(W_hh, U(o_Whhp), 1024);
  bias_perm_kernel<<<dim3(16), 256, 0, stream>>>(b_ih, b_hh, F(o_bsum));
  cvt_transpose_kernel<<<dim3(8, 48), 256, 0, stream>>>(Wout, U(o_WoutT), 1536, 256);
  cvt_kernel<<<dim3(4096), 256, 0, stream>>>(enc, U(a_enc), 32 * 256 * 1024);

  // ---- embedding + char->pseudoword ----
  cvt_transpose_kernel<<<dim3(32, 4), 256, 0, stream>>>(Wc, U(a_wl), 128, 1024);
  embed_kernel<<<dim3(32000), dim3(128), 0, stream>>>(tgt, char_emb, pre_pos, U(s_emb));
  gemm(U(s_emb), U(a_wl), bc, nullptr, U(s_hbf), 32000, 1024, 128, 128, 128, 1024, 1, 0);
  pool_bert_ln_kernel<<<dim3(6400), 256, 0, stream>>>(
      U(s_hbf), tmask, bert_pos, bert_tok, eln_g, eln_b, F(a_x), U(a_xbf), F(o_smask));

  // ---- transformer layers ----
  for (int l = 0; l < 6; ++l) {
    cvt_transpose_kernel<<<dim3(96, 32), 256, 0, stream>>>(Wqkv + (size_t)l * 1024 * 3072, U(wl_qkv), 1024, 3072);
    cvt_transpose_kernel<<<dim3(32, 32), 256, 0, stream>>>(Wo + (size_t)l * 1024 * 1024, U(wl_wo), 1024, 1024);
    cvt_transpose_kernel<<<dim3(32, 32), 256, 0, stream>>>(Cq + (size_t)l * 1024 * 1024, U(wl_cq), 1024, 1024);
    cvt_transpose_kernel<<<dim3(64, 32), 256, 0, stream>>>(Ckv + (size_t)l * 1024 * 2048, U(wl_ckv), 1024, 2048);
    cvt_transpose_kernel<<<dim3(32, 32), 256, 0, stream>>>(Co + (size_t)l * 1024 * 1024, U(wl_co), 1024, 1024);
    cvt_transpose_kernel<<<dim3(64, 32), 256, 0, stream>>>(W1 + (size_t)l * 1024 * 2048, U(wl_w1), 1024, 2048);
    cvt_transpose_kernel<<<dim3(32, 64), 256, 0, stream>>>(W2 + (size_t)l * 2048 * 1024, U(wl_w2), 2048, 1024);

    // self-attention
    gemm(U(a_xbf), U(wl_qkv), bqkv + l * 3072, nullptr, U(s_qkv), 6400, 3072, 1024, 1024, 1024, 3072, 0, 0);
    vtrans_kernel<<<dim3(512), 256, 0, stream>>>(U(s_qkv), 3072, 2048, 200, U(s_vT));
    scores_kernel<<<dim3(1664), 256, 0, stream>>>(
        U(s_qkv), 3072, U(s_qkv), 3072, 1024, 200, F(o_smask), U(s_P), 1);
    pv_kernel<<<dim3(1664), 256, 0, stream>>>(U(s_P), U(s_vT), U(s_S2));
    gemm(U(s_S2), U(wl_wo), bo + l * 1024, F(s_o32), nullptr, 6400, 1024, 1024, 1024, 1024, 1024, 0, 0);
    resid_ln_kernel<<<dim3(6400), 256, 0, stream>>>(F(a_x), F(s_o32), ln1g + l * 1024, ln1b + l * 1024, U(a_xbf));

    // cross-attention
    gemm(U(a_xbf), U(wl_cq), cbq + l * 1024, nullptr, U(s_qkv), 6400, 1024, 1024, 1024, 1024, 1024, 0, 0);
    gemm(U(a_enc), U(wl_ckv), cbkv + l * 2048, nullptr, U(s_kvc), 8192, 2048, 1024, 1024, 1024, 2048, 0, 0);
    vtrans_kernel<<<dim3(512), 256, 0, stream>>>(U(s_kvc), 2048, 1024, 256, U(s_vT));
    scores_kernel<<<dim3(1664), 256, 0, stream>>>(
        U(s_qkv), 1024, U(s_kvc), 2048, 0, 256, encmask, U(s_P), 0);
    pv_kernel<<<dim3(1664), 256, 0, stream>>>(U(s_P), U(s_vT), U(s_S2));
    gemm(U(s_S2), U(wl_co), cbo + l * 1024, F(s_o32), nullptr, 6400, 1024, 1024, 1024, 1024, 1024, 0, 0);
    resid_ln_kernel<<<dim3(6400), 256, 0, stream>>>(F(a_x), F(s_o32), ln2g + l * 1024, ln2b + l * 1024, U(a_xbf));

    // FFN
    gemm(U(a_xbf), U(wl_w1), b1 + l * 2048, nullptr, U(s_S2), 6400, 2048, 1024, 1024, 1024, 2048, 1, 0);
    gemm(U(s_S2), U(wl_w2), b2 + l * 1024, F(s_o32), nullptr, 6400, 1024, 2048, 2048, 2048, 1024, 0, 0);
    resid_ln_kernel<<<dim3(6400), 256, 0, stream>>>(F(a_x), F(s_o32), ln3g + l * 1024, ln3b + l * 1024, U(a_xbf));
  }

  // ---- nar proj -> char states ----
  cvt_transpose_kernel<<<dim3(80, 32), 256, 0, stream>>>(Wnar, U(a_wl), 1024, 2560);
  gemm(U(a_xbf), U(a_wl), bnar, nullptr, U(o_cs), 6400, 2560, 1024, 1024, 1024, 2560, 0, 0);

  // ---- LSTM input (time-major) + time-major char states ----
  lstmin_kernel<<<dim3(32000), dim3(640), 0, stream>>>(tgt, char_emb, U(o_cs), U(b_lin), U(o_cst));

  // ---- chunked xproj GEMM + LSTM ----
  for (int c = 0; c < 2; ++c) {
    gemm(U(b_lin) + (size_t)c * 16000 * 640, U(o_Wihp), F(o_bsum), nullptr, U(b_xpj),
         16000, 4096, 640, 640, 640, 4096, 0, 0);
    flags_reset_kernel<<<dim3(1), 256, 0, stream>>>(flags);
    const u16* xprojp = U(b_xpj);
    const u16* Wpp = U(o_Whhp);
    u16* loutp = U(o_lout);
    const u16* zbufp = U(o_zbuf);
    float* cbufp = F(o_cbuf);
    unsigned* flagsp = flags;
    int t0 = c * 500, ns = 500;
    void* kargs[] = { &xprojp, &Wpp, &loutp, &zbufp, &cbufp, &flagsp, &t0, &ns };
    hipLaunchCooperativeKernel(lstm_kernel, dim3(64), dim3(256), kargs, 0u, stream);
  }

  // ---- output projection (time-major rows) + NLL ----
  gemm(U(o_lout), U(o_WoutT), bout, F(b_xpj), nullptr, 32000, 256, 1024, 1024, 1536, 256, 0, 0);
  gemm(U(o_cst), U(o_WoutT) + 1024, nullptr, F(b_xpj), nullptr, 32000, 256, 512, 512, 1536, 256, 0, 1);
  nll_kernel<<<dim3(2000), 256, 0, stream>>>(F(b_xpj), tgt, tmask, accum);
  finalize_kernel<<<dim3(1), dim3(64), 0, stream>>>(accum, (float*)d_out);
}